// Round 13
// baseline (255.979 us; speedup 1.0000x reference)
//
#include <hip/hip_runtime.h>

#define B_ 8192
#define D_ 512
#define M_ 1000
#define H_ 8
#define LOG2E 1.4426950408889634f

typedef unsigned short u16;
typedef __attribute__((ext_vector_type(8))) short bf16x8;
typedef __attribute__((ext_vector_type(4))) float f32x4;

__device__ __forceinline__ float bf2f(u16 u) {
    union { unsigned u; float f; } c; c.u = ((unsigned)u) << 16; return c.f;
}
__device__ __forceinline__ u16 f2bf(float f) {
    union { float f; unsigned u; } c; c.f = f;
    unsigned r = (c.u + 0x7fffu + ((c.u >> 16) & 1u)) >> 16;
    return (u16)r;
}
__device__ __forceinline__ unsigned f2bf_fast_u(float f) {
    union { float f; unsigned u; } c; c.f = f;
    return (c.u + 0x8000u) >> 16;
}
__device__ __forceinline__ float wave_sum(float v) {
#pragma unroll
    for (int off = 32; off > 0; off >>= 1) v += __shfl_xor(v, off);
    return v;
}

// ---------------------------------------------------------------------------
// bf16 MFMA GEMM core (R8-FINAL config: 64x64 tile, BK=64, 2-barrier).
// CLOSED after 4 experiments (R3/R4/R7/R9). LDS passed in (R7 lesson);
// bx/by passed for fused-grid remapping. 4 waves each 32x32.
// VTOUT: cols >= 512 written transposed to VT[(col-512)*1024+row], zero-padded.
// ---------------------------------------------------------------------------
template<bool RELU, bool WF32, bool VTOUT>
__device__ __forceinline__ void gemm_core(
    int bx, int by, u16* As, u16* Bs,
    const u16* __restrict__ A0, const u16* __restrict__ A1,
    const u16* __restrict__ A2, int lda0, int lda1, int lda2,
    const u16* __restrict__ W0, const u16* __restrict__ W1,
    const u16* __restrict__ W2, int ldw0, int ldw1, int ldw2,
    int kb1, int kb2,
    const float* __restrict__ bias, float bscale, float cscale,
    float* __restrict__ Cf, u16* __restrict__ Cb, u16* __restrict__ VT,
    int M, int N, int K, int ldc)
{
    const int m0 = by * 64, n0 = bx * 64;
    if (m0 >= M || n0 >= N) return;
    const int t = threadIdx.x, w = t >> 6, l = t & 63;
    const int wm = (w >> 1) * 32, wn = (w & 1) * 32;
    const int li = l & 15, quad = l >> 4;

    f32x4 acc[2][2];
#pragma unroll
    for (int i = 0; i < 2; ++i)
#pragma unroll
        for (int j = 0; j < 2; ++j) acc[i][j] = (f32x4){0.f, 0.f, 0.f, 0.f};

    for (int k0 = 0; k0 < K; k0 += 64) {
        const u16* Ab; const u16* Wb; int ldab, ldwb, ko;
        if (k0 < kb1)      { Ab = A0; ldab = lda0; Wb = W0; ldwb = ldw0; ko = k0; }
        else if (k0 < kb2) { Ab = A1; ldab = lda1; Wb = W1; ldwb = ldw1; ko = k0 - kb1; }
        else               { Ab = A2; ldab = lda2; Wb = W2; ldwb = ldw2; ko = k0 - kb2; }
#pragma unroll
        for (int i = 0; i < 2; ++i) {
            const int rl = w * 16 + i * 8 + (l >> 3);
            const int ck = (l & 7) ^ (rl & 7);
            int ga = m0 + rl; ga = ga < M ? ga : M - 1;
            __builtin_amdgcn_global_load_lds(
                (const __attribute__((address_space(1))) void*)(Ab + (size_t)ga * ldab + ko + ck * 8),
                (__attribute__((address_space(3))) void*)(As + (w * 16 + i * 8) * 64),
                16, 0, 0);
        }
#pragma unroll
        for (int i = 0; i < 2; ++i) {
            const int rl = w * 16 + i * 8 + (l >> 3);
            const int ck = (l & 7) ^ (rl & 7);
            int gb = n0 + rl; gb = gb < N ? gb : N - 1;
            __builtin_amdgcn_global_load_lds(
                (const __attribute__((address_space(1))) void*)(Wb + (size_t)gb * ldwb + ko + ck * 8),
                (__attribute__((address_space(3))) void*)(Bs + (w * 16 + i * 8) * 64),
                16, 0, 0);
        }
        __syncthreads();
#pragma unroll
        for (int ks = 0; ks < 2; ++ks) {
            const int ch = ks * 4 + quad;
            bf16x8 af[2], bfr[2];
#pragma unroll
            for (int mt = 0; mt < 2; ++mt) {
                const int r = wm + mt * 16 + li;
                af[mt] = *(const bf16x8*)(As + r * 64 + ((ch ^ (r & 7)) * 8));
            }
#pragma unroll
            for (int nt = 0; nt < 2; ++nt) {
                const int r = wn + nt * 16 + li;
                bfr[nt] = *(const bf16x8*)(Bs + r * 64 + ((ch ^ (r & 7)) * 8));
            }
#pragma unroll
            for (int mt = 0; mt < 2; ++mt)
#pragma unroll
                for (int nt = 0; nt < 2; ++nt)
                    acc[mt][nt] = __builtin_amdgcn_mfma_f32_16x16x32_bf16(
                        af[mt], bfr[nt], acc[mt][nt], 0, 0, 0);
        }
        __syncthreads();
    }

    float bv[2];
#pragma unroll
    for (int nt = 0; nt < 2; ++nt) bv[nt] = bias[n0 + wn + nt * 16 + li] * bscale;
#pragma unroll
    for (int mt = 0; mt < 2; ++mt) {
        const int row0 = m0 + wm + mt * 16 + quad * 4;
#pragma unroll
        for (int nt = 0; nt < 2; ++nt) {
            const int col = n0 + wn + nt * 16 + li;
            if (VTOUT && col >= 512) {
                ushort4 pk;
                u16 pv[4];
#pragma unroll
                for (int r = 0; r < 4; ++r) {
                    float v = acc[mt][nt][r] * cscale + bv[nt];
                    pv[r] = (row0 + r < M_) ? f2bf(v) : (u16)0;
                }
                pk.x = pv[0]; pk.y = pv[1]; pk.z = pv[2]; pk.w = pv[3];
                *(ushort4*)(VT + (size_t)(col - 512) * 1024 + row0) = pk;
            } else {
#pragma unroll
                for (int r = 0; r < 4; ++r) {
                    const int row = row0 + r;
                    if (row >= M) continue;
                    float v = acc[mt][nt][r] * cscale + bv[nt];
                    if (RELU) v = fmaxf(v, 0.f);
                    Cb[(size_t)row * ldc + col] = f2bf(v);
                    if (WF32) Cf[(size_t)row * ldc + col] = v;
                }
            }
        }
    }
}

template<bool RELU, bool WF32>
__launch_bounds__(256)
__global__ void mgemm(const u16* __restrict__ A0, const u16* __restrict__ A1,
                      const u16* __restrict__ A2, int lda0, int lda1, int lda2,
                      const u16* __restrict__ W0, const u16* __restrict__ W1,
                      const u16* __restrict__ W2, int ldw0, int ldw1, int ldw2,
                      int kb1, int kb2,
                      const float* __restrict__ bias, float bscale, float cscale,
                      float* __restrict__ Cf, u16* __restrict__ Cb,
                      int M, int N, int K, int ldc)
{
    __shared__ u16 As[64 * 64];
    __shared__ u16 Bs[64 * 64];
    gemm_core<RELU, WF32, false>(blockIdx.x, blockIdx.y, As, Bs,
                                 A0, A1, A2, lda0, lda1, lda2,
                                 W0, W1, W2, ldw0, ldw1, ldw2, kb1, kb2,
                                 bias, bscale, cscale, Cf, Cb, nullptr, M, N, K, ldc);
}

// ---------------------------------------------------------------------------
// enc + KV-projection + 3 weight-folds fused in ONE dispatch (single
// kernel-scope LDS). Grid (16,128,2): z=0 enc; z=1: KV + 3 folds.
// ---------------------------------------------------------------------------
__launch_bounds__(256)
__global__ void megagemm(const u16* __restrict__ obs_bf, const u16* __restrict__ w_enc1,
                         const float* __restrict__ enc_b1, u16* __restrict__ hbuf,
                         const u16* __restrict__ wmem_bf, const u16* __restrict__ w_k,
                         const float* __restrict__ bkv, u16* __restrict__ KVbuf,
                         u16* __restrict__ VTb,
                         const u16* __restrict__ w_q, const u16* __restrict__ w_tr1,
                         const u16* __restrict__ w_e2t, const u16* __restrict__ w_wot,
                         u16* __restrict__ w_qe, u16* __restrict__ w_ae,
                         u16* __restrict__ w_co)
{
    __shared__ u16 As[64 * 64];
    __shared__ u16 Bs[64 * 64];
    const int bx = blockIdx.x, by = blockIdx.y;
    if (blockIdx.z == 0) {
        gemm_core<true, false, false>(bx, by, As, Bs,
            obs_bf, obs_bf, obs_bf, 512, 512, 512,
            w_enc1, w_enc1, w_enc1, 512, 512, 512, 512, 512,
            enc_b1, 1.f, 1.f, nullptr, hbuf, nullptr, B_, 512, 512, 512);
    } else {
        if (by < 16) {
            gemm_core<false, false, true>(bx, by, As, Bs,
                wmem_bf, wmem_bf, wmem_bf, 512, 512, 512,
                w_k, w_k, w_k, 512, 512, 512, 512, 512,
                bkv, 1.f, 1.f, nullptr, KVbuf, VTb, 1024, 1024, 512, 1024);
        } else if (by < 24) {
            gemm_core<false, false, false>(bx, by - 16, As, Bs,
                w_q, w_q, w_q, 512, 512, 512,
                w_e2t, w_e2t, w_e2t, 512, 512, 512, 512, 512,
                bkv, 0.f, 1.0f, nullptr, w_qe, nullptr, 512, 512, 512, 512);
        } else if (by < 32) {
            gemm_core<false, false, false>(bx, by - 24, As, Bs,
                w_tr1, w_tr1, w_tr1, 576, 576, 576,
                w_e2t, w_e2t, w_e2t, 512, 512, 512, 512, 512,
                bkv, 0.f, 0.7f, nullptr, w_ae, nullptr, 512, 512, 512, 512);
        } else if (by < 40) {
            gemm_core<false, false, false>(bx, by - 32, As, Bs,
                w_tr1, w_tr1, w_tr1, 576, 576, 576,
                w_wot, w_wot, w_wot, 512, 512, 512, 512, 512,
                bkv, 0.f, 0.3f, nullptr, w_co, nullptr, 512, 512, 512, 512);
        }
    }
}

// ---------------------------------------------------------------------------
// Fused flash attention. R13: 8-wave blocks (512 thr), each wave owns 16
// q-rows. R12 post-mortem: conflicts are NOT on the critical path (1.6M->1.0M
// with zero time delta); profile is latency-bound (MFMA 19%/VALU 43%/Occ 17%
// at 2 waves/SIMD). Same grid 512 = 2 blocks/CU, but 512-thr blocks give
// 16 waves/CU = 4 waves/SIMD -> 2x TLP to hide the serial QK->exp->PV chain
// (the R2-proven 8-wave mechanism). Dataflow/layouts byte-equivalent:
// XOR-swizzled P (16KB, rows=128), packed b64 P writes, Q-prologue (R11),
// T5 setprio (R10). __launch_bounds__(512,2): min-BLOCKS -> 128-VGPR cap.
// ---------------------------------------------------------------------------
__launch_bounds__(512, 2)
__global__ void attn_kernel(const u16* __restrict__ hn, const u16* __restrict__ w_qe,
                            const float* __restrict__ bqe,
                            const u16* __restrict__ KV,
                            const u16* __restrict__ VT, u16* __restrict__ ctx)
{
    __shared__ u16 Ks[2][64 * 64];
    __shared__ u16 Vs[2][64 * 64];
    __shared__ u16 P[128 * 64];           // 16 KB; q-tile [128][64] then P rows
    const int t = threadIdx.x, w = t >> 6, l = t & 63;
    const int h = blockIdx.y;
    const int q0b = blockIdx.x * 128;
    u16* Pw = P + w * 1024;               // wave's 16 P rows
    const int li = l & 15, quad = l >> 4;

    // stage one 64-key chunk of K and V: 512 threads x 16B = 8KB each, 1 issue.
    auto stage = [&](int kc, int buf) {
        {
            const int r = t >> 3;
            const int ck = (t & 7) ^ (r & 7);
            __builtin_amdgcn_global_load_lds(
                (const __attribute__((address_space(1))) void*)(KV + (size_t)(kc + r) * 1024 + h * 64 + ck * 8),
                (__attribute__((address_space(3))) void*)(&Ks[buf][t * 8]),
                16, 0, 0);
        }
        {
            const int r = t >> 3;
            const int ck = (t & 7) ^ (r & 7);
            __builtin_amdgcn_global_load_lds(
                (const __attribute__((address_space(1))) void*)(VT + (size_t)(h * 64 + r) * 1024 + kc + ck * 8),
                (__attribute__((address_space(3))) void*)(&Vs[buf][t * 8]),
                16, 0, 0);
        }
    };

    // ---- Q-projection prologue: qtile = hn[q0b..+128] @ w_qe[h*64..+64]^T + bqe
    {
        u16* Ksf = &Ks[0][0];             // 128x64 A-tile (spans Ks[0..1], 16KB)
        u16* Bsf = &Vs[0][0];             // 64x64 B-tile (8KB)
        f32x4 qacc[4];
#pragma unroll
        for (int nt = 0; nt < 4; ++nt) qacc[nt] = (f32x4){0.f, 0.f, 0.f, 0.f};

        for (int k0 = 0; k0 < 512; k0 += 64) {
#pragma unroll
            for (int i = 0; i < 2; ++i) {
                const int f = i * 512 + t;
                const int rl = f >> 3;                       // 0..127
                const int ck = (f & 7) ^ (rl & 7);
                __builtin_amdgcn_global_load_lds(
                    (const __attribute__((address_space(1))) void*)(hn + (size_t)(q0b + rl) * 512 + k0 + ck * 8),
                    (__attribute__((address_space(3))) void*)(Ksf + f * 8),
                    16, 0, 0);
            }
            {
                const int rl = t >> 3;                       // 0..63
                const int ck = (t & 7) ^ (rl & 7);
                __builtin_amdgcn_global_load_lds(
                    (const __attribute__((address_space(1))) void*)(w_qe + (size_t)(h * 64 + rl) * 512 + k0 + ck * 8),
                    (__attribute__((address_space(3))) void*)(Bsf + t * 8),
                    16, 0, 0);
            }
            __syncthreads();
            __builtin_amdgcn_s_setprio(1);
#pragma unroll
            for (int ks = 0; ks < 2; ++ks) {
                const int ch = ks * 4 + quad;
                const int r = w * 16 + li;                   // wave's A row
                const bf16x8 af = *(const bf16x8*)(Ksf + r * 64 + ((ch ^ (r & 7)) * 8));
                bf16x8 bfr[4];
#pragma unroll
                for (int nt = 0; nt < 4; ++nt) {
                    const int rb = nt * 16 + li;
                    bfr[nt] = *(const bf16x8*)(Bsf + rb * 64 + ((ch ^ (rb & 7)) * 8));
                }
#pragma unroll
                for (int nt = 0; nt < 4; ++nt)
                    qacc[nt] = __builtin_amdgcn_mfma_f32_16x16x32_bf16(
                        af, bfr[nt], qacc[nt], 0, 0, 0);
            }
            __builtin_amdgcn_s_setprio(0);
            __syncthreads();              // Ks/Vs reads drained
        }

        // Ks/Vs now free: issue K/V chunk-0 staging early
        stage(0, 0);

        // write q-tile rows w*16+quad*4+r into P (XOR layout)
#pragma unroll
        for (int nt = 0; nt < 4; ++nt) {
            const int col = nt * 16 + li;
            const float bv = bqe[h * 64 + col];
#pragma unroll
            for (int r = 0; r < 4; ++r) {
                const int row = w * 16 + quad * 4 + r;
                P[row * 64 + (((2 * nt + (li >> 3)) ^ (row & 7)) * 8) + (li & 7)] =
                    f2bf(qacc[nt][r] + bv);
            }
        }
    }

    // aq fragment loads (row w*16+li; written by this wave only -> intra-wave)
    bf16x8 aq[2];
#pragma unroll
    for (int ks = 0; ks < 2; ++ks) {
        const int row = w * 16 + li;
        aq[ks] = *(const bf16x8*)(P + row * 64 + (((ks * 4 + quad) ^ (li & 7)) * 8));
    }

    bf16x8 ones;
#pragma unroll
    for (int i = 0; i < 8; ++i) ones[i] = (short)0x3F80;

    f32x4 oacc[4];
    f32x4 lacc = (f32x4){0.f, 0.f, 0.f, 0.f};
#pragma unroll
    for (int nt = 0; nt < 4; ++nt) oacc[nt] = (f32x4){0.f, 0.f, 0.f, 0.f};

    for (int ic = 0; ic < 16; ++ic) {
        const int kc = ic * 64;
        __syncthreads();          // chunk-ic staging drained; aq reads done (ic=0)
        if (ic < 15) stage(kc + 64, (ic + 1) & 1);
        const u16* ksb = &Ks[ic & 1][0];
        const u16* vsb = &Vs[ic & 1][0];

        f32x4 s[4];
#pragma unroll
        for (int kmt = 0; kmt < 4; ++kmt) s[kmt] = (f32x4){0.f, 0.f, 0.f, 0.f};
        __builtin_amdgcn_s_setprio(1);
#pragma unroll
        for (int ks = 0; ks < 2; ++ks) {
            const int ch = ks * 4 + quad;
            bf16x8 bk[4];
#pragma unroll
            for (int kmt = 0; kmt < 4; ++kmt) {
                const int key = kmt * 16 + li;
                bk[kmt] = *(const bf16x8*)(ksb + key * 64 + ((ch ^ (key & 7)) * 8));
            }
#pragma unroll
            for (int kmt = 0; kmt < 4; ++kmt)
                s[kmt] = __builtin_amdgcn_mfma_f32_16x16x32_bf16(
                    bk[kmt], aq[ks], s[kmt], 0, 0, 0);
        }
        __builtin_amdgcn_s_setprio(0);
        if (kc == 960) {
#pragma unroll
            for (int kmt = 2; kmt < 4; ++kmt)
#pragma unroll
                for (int r = 0; r < 4; ++r) {
                    const int key_local = kmt * 16 + quad * 4 + r;
                    if (960 + key_local >= M_) s[kmt][r] = -3.0e38f;
                }
        }
        // exp + pack: 4 consecutive keys -> one b64 write (XOR layout).
        // C[key][qrow]: col=li=qrow(0..15), row=quad*4+r=key within kmt's 16.
#pragma unroll
        for (int kmt = 0; kmt < 4; ++kmt) {
            const unsigned b0 = f2bf_fast_u(exp2f(s[kmt][0]));
            const unsigned b1 = f2bf_fast_u(exp2f(s[kmt][1]));
            const unsigned b2w = f2bf_fast_u(exp2f(s[kmt][2]));
            const unsigned b3 = f2bf_fast_u(exp2f(s[kmt][3]));
            const int chunk = (2 * kmt + (quad >> 1)) ^ (li & 7);
            const int off = li * 64 + chunk * 8 + (quad & 1) * 4;
            *(uint2*)(Pw + off) = make_uint2(b0 | (b1 << 16), b2w | (b3 << 16));
        }
        __builtin_amdgcn_s_setprio(1);
#pragma unroll
        for (int ks = 0; ks < 2; ++ks) {
            const int ch = ks * 4 + quad;
            const bf16x8 ap = *(const bf16x8*)(Pw + li * 64 + ((ch ^ (li & 7)) * 8));
            lacc = __builtin_amdgcn_mfma_f32_16x16x32_bf16(ap, ones, lacc, 0, 0, 0);
#pragma unroll
            for (int nt = 0; nt < 4; ++nt) {
                const int dh = nt * 16 + li;
                const bf16x8 bvv = *(const bf16x8*)(vsb + dh * 64 + ((ch ^ (dh & 7)) * 8));
                oacc[nt] = __builtin_amdgcn_mfma_f32_16x16x32_bf16(
                    ap, bvv, oacc[nt], 0, 0, 0);
            }
        }
        __builtin_amdgcn_s_setprio(0);
    }

    // epilogue: qrow = quad*4+r within wave's 16 rows; dh = nt*16+li
#pragma unroll
    for (int r = 0; r < 4; ++r) {
        const int row = q0b + w * 16 + quad * 4 + r;
        const float inv = 1.0f / lacc[r];
#pragma unroll
        for (int nt = 0; nt < 4; ++nt)
            ctx[(size_t)row * 512 + h * 64 + nt * 16 + li] = f2bf(oacc[nt][r] * inv);
    }
}

__launch_bounds__(256)
__global__ void ln_bf(u16* __restrict__ X, const float* __restrict__ g,
                      const float* __restrict__ be, int rows)
{
    const int row = blockIdx.x * 4 + (threadIdx.x >> 6);
    const int lane = threadIdx.x & 63;
    if (row >= rows) return;
    u16* p = X + (size_t)row * 512 + lane * 8;
    uint4 d = *(const uint4*)p;
    const unsigned dd[4] = {d.x, d.y, d.z, d.w};
    float v[8];
#pragma unroll
    for (int i = 0; i < 4; ++i) {
        v[2 * i]     = bf2f((u16)(dd[i] & 0xffffu));
        v[2 * i + 1] = bf2f((u16)(dd[i] >> 16));
    }
    float s = 0.f;
#pragma unroll
    for (int i = 0; i < 8; ++i) s += v[i];
    s = wave_sum(s);
    const float mu = s * (1.0f / 512.0f);
    float vs = 0.f;
#pragma unroll
    for (int i = 0; i < 8; ++i) { v[i] -= mu; vs += v[i] * v[i]; }
    vs = wave_sum(vs);
    const float r = rsqrtf(vs * (1.0f / 512.0f) + 1e-5f);
    const float* gp = g + lane * 8;
    const float* bp = be + lane * 8;
    unsigned o[4];
#pragma unroll
    for (int i = 0; i < 4; ++i) {
        const u16 lo = f2bf(v[2 * i] * r * gp[2 * i] + bp[2 * i]);
        const u16 hi = f2bf(v[2 * i + 1] * r * gp[2 * i + 1] + bp[2 * i + 1]);
        o[i] = (unsigned)lo | ((unsigned)hi << 16);
    }
    *(uint4*)p = make_uint4(o[0], o[1], o[2], o[3]);
}

// one-dispatch prep: weight converts (0-6), transposes (7-8), activation
// converts (9-11), bias folds (12-13)  (R6-exact)
__launch_bounds__(256)
__global__ void prep_all(const float* enc_w1, const float* wk_f, const float* wv_f,
                         const float* tr_w2, const float* q_w1, const float* wq,
                         const float* tr_w1, const float* enc_w2, const float* wo,
                         const float* obs, const float* wmem, const float* ego,
                         const float* bk, const float* bvv, const float* bq,
                         const float* enc_b2, const float* trb1, const float* bo,
                         u16* w_enc1, u16* w_k, u16* w_v, u16* w_tr2, u16* w_qh,
                         u16* w_q, u16* w_tr1, u16* w_e2t, u16* w_wot,
                         u16* obs_bf, u16* wmem_bf, u16* ego64,
                         float* bkv, float* bqe, float* btr)
{
    __shared__ float tl[64][65];
    const int seg = blockIdx.y;
    const int t = threadIdx.x;
    const int bx = blockIdx.x;

    if (seg <= 5) {
        const float* s; u16* d; int n; float sc = 1.0f;
        switch (seg) {
            case 0: s = enc_w1; d = w_enc1; n = 262144; break;
            case 1: s = wk_f;   d = w_k;    n = 262144; break;
            case 2: s = wv_f;   d = w_v;    n = 262144; break;
            case 3: s = tr_w2;  d = w_tr2;  n = 262144; break;
            case 4: s = q_w1;   d = w_qh;   n = 65536;  break;
            default: s = wq;    d = w_q;    n = 262144; sc = 0.125f * LOG2E; break;
        }
        const int i0 = (bx * 256 + t) * 4;
        if (i0 + 3 < n) {
            const float4 v = *(const float4*)(s + i0);
            ushort4 o;
            o.x = f2bf(v.x * sc); o.y = f2bf(v.y * sc);
            o.z = f2bf(v.z * sc); o.w = f2bf(v.w * sc);
            *(ushort4*)(d + i0) = o;
        }
    } else if (seg == 6) {
#pragma unroll
        for (int k = 0; k < 4; ++k) {
            const int i = (bx * 256 + t) * 4 + k;
            if (i < 294912) {
                const int r = i / 576, c = i - r * 576;
                w_tr1[i] = (c < 528) ? f2bf(tr_w1[r * 528 + c]) : (u16)0;
            }
        }
    } else if (seg <= 8) {
        if (bx >= 64) return;
        const float* S = (seg == 7) ? enc_w2 : wo;
        u16* D = (seg == 7) ? w_e2t : w_wot;
        const int r0 = (bx >> 3) * 64, c0 = (bx & 7) * 64;
#pragma unroll
        for (int i = 0; i < 16; ++i) {
            const int idx = t + i * 256;
            tl[idx >> 6][idx & 63] = S[(size_t)(r0 + (idx >> 6)) * 512 + c0 + (idx & 63)];
        }
        __syncthreads();
#pragma unroll
        for (int i = 0; i < 16; ++i) {
            const int idx = t + i * 256;
            const int c = idx >> 6, r = idx & 63;
            D[(size_t)(c0 + c) * 512 + r0 + r] = f2bf(tl[r][c]);
        }
    } else if (seg == 9) {
        const int nth = gridDim.x * 256;
        for (int i = bx * 256 + t; i < B_ * 512 / 4; i += nth) {
            const float4 v = ((const float4*)obs)[i];
            ushort4 o;
            o.x = f2bf(v.x); o.y = f2bf(v.y); o.z = f2bf(v.z); o.w = f2bf(v.w);
            ((ushort4*)obs_bf)[i] = o;
        }
    } else if (seg == 10) {
        const int nth = gridDim.x * 256;
        for (int i = bx * 256 + t; i < M_ * 512 / 4; i += nth) {
            const float4 v = ((const float4*)wmem)[i];
            ushort4 o;
            o.x = f2bf(v.x); o.y = f2bf(v.y); o.z = f2bf(v.z); o.w = f2bf(v.w);
            ((ushort4*)wmem_bf)[i] = o;
        }
    } else if (seg == 11) {
        const int nth = gridDim.x * 256;
        for (int i = bx * 256 + t; i < B_ * 64; i += nth) {
            const int b = i >> 6, j = i & 63;
            ego64[(size_t)b * 64 + j] = (j < 16) ? f2bf(ego[b * 16 + j]) : (u16)0;
        }
        const int tid = bx * 256 + t;
        if (tid < 1024) bkv[tid] = (tid < 512) ? bk[tid] : bvv[tid - 512];
    } else {
        if (bx >= 128) return;
        const int i = bx * 4 + (t >> 6);
        const int lane = t & 63;
        float s = 0.f;
        if (seg == 12) {
            const float* wr = wq + (size_t)i * 512 + lane * 8;
#pragma unroll
            for (int j = 0; j < 8; ++j) s += wr[j] * enc_b2[lane * 8 + j];
            s = wave_sum(s);
            if (lane == 0) bqe[i] = 0.125f * LOG2E * (bq[i] + s);
        } else {
            const float* wr = tr_w1 + (size_t)i * 528 + lane * 8;
#pragma unroll
            for (int j = 0; j < 8; ++j)
                s += wr[j] * (0.7f * enc_b2[lane * 8 + j] + 0.3f * bo[lane * 8 + j]);
            s = wave_sum(s);
            if (lane == 0) btr[i] = trb1[i] + s;
        }
    }
}

__global__ void quality_bf(const u16* __restrict__ qh, const float* __restrict__ w2,
                           const float* __restrict__ b2, float* __restrict__ outq,
                           int rows)
{
    const int row = blockIdx.x * 4 + (threadIdx.x >> 6);
    const int lane = threadIdx.x & 63;
    if (row >= rows) return;
    const u16* p = qh + (size_t)row * 128;
    float s = bf2f(p[lane]) * w2[lane] + bf2f(p[64 + lane]) * w2[64 + lane];
    s = wave_sum(s);
    if (lane == 0) outq[row] = 1.0f / (1.0f + expf(-(s + b2[0])));
}

__global__ void compact_kernel(const float* __restrict__ q,
                               int* __restrict__ list, int* __restrict__ cnt)
{
    __shared__ int wtot[16];
    __shared__ int sbase;
    const int t = threadIdx.x, w = t >> 6, lane = t & 63;
    if (t == 0) sbase = 0;
    __syncthreads();
    for (int c = 0; c < B_; c += 1024) {
        const int idx = c + t;
        const bool pred = (q[idx] > 0.7f);
        const unsigned long long bal = __ballot(pred);
        const int prefix = __popcll(bal & ((1ull << lane) - 1ull));
        if (lane == 0) wtot[w] = __popcll(bal);
        __syncthreads();
        int woff = 0;
        for (int i = 0; i < w; ++i) woff += wtot[i];
        if (pred) list[sbase + woff + prefix] = idx;
        __syncthreads();
        if (t == 0) {
            int tot = 0;
            for (int i = 0; i < 16; ++i) tot += wtot[i];
            sbase += tot;
        }
        __syncthreads();
    }
    if (t == 0) *cnt = sbase;
}

__global__ void update_memory_kernel(const float* __restrict__ mem,
                                     const float* __restrict__ ns,
                                     const int* __restrict__ upd,
                                     const int* __restrict__ list,
                                     const int* __restrict__ cnt,
                                     float* __restrict__ outmem)
{
    const int m = blockIdx.x;
    const int t = threadIdx.x;
    const int c4 = t * 4;
    float4 r = *(const float4*)(mem + (size_t)m * D_ + c4);
    const int n = *cnt;
    for (int i = 0; i < n; ++i) {
        const int b = list[i];
        if (upd[b] == m) {
            const float4 s = *(const float4*)(ns + (size_t)b * D_ + c4);
            r.x = 0.9f * r.x + 0.1f * s.x;
            r.y = 0.9f * r.y + 0.1f * s.y;
            r.z = 0.9f * r.z + 0.1f * s.z;
            r.w = 0.9f * r.w + 0.1f * s.w;
        }
    }
    *(float4*)(outmem + (size_t)m * D_ + c4) = r;
}

extern "C" void kernel_launch(void* const* d_in, const int* in_sizes, int n_in,
                              void* d_out, int out_size, void* d_ws, size_t ws_size,
                              hipStream_t stream)
{
    const float* obs    = (const float*)d_in[0];
    const float* ego    = (const float*)d_in[1];
    const float* wmem   = (const float*)d_in[2];
    const float* enc_w1 = (const float*)d_in[3];
    const float* enc_b1 = (const float*)d_in[4];
    const float* enc_g  = (const float*)d_in[5];
    const float* enc_be = (const float*)d_in[6];
    const float* enc_w2 = (const float*)d_in[7];
    const float* enc_b2 = (const float*)d_in[8];
    const float* wq = (const float*)d_in[9];
    const float* bq = (const float*)d_in[10];
    const float* wk_f = (const float*)d_in[11];
    const float* bk = (const float*)d_in[12];
    const float* wv_f = (const float*)d_in[13];
    const float* bvv = (const float*)d_in[14];
    const float* wo = (const float*)d_in[15];
    const float* bo = (const float*)d_in[16];
    const float* tr_w1 = (const float*)d_in[17];
    const float* tr_b1 = (const float*)d_in[18];
    const float* tr_g  = (const float*)d_in[19];
    const float* tr_be = (const float*)d_in[20];
    const float* tr_w2 = (const float*)d_in[21];
    const float* tr_b2 = (const float*)d_in[22];
    const float* q_w1 = (const float*)d_in[23];
    const float* q_b1 = (const float*)d_in[24];
    const float* q_w2 = (const float*)d_in[25];
    const float* q_b2 = (const float*)d_in[26];
    const int*   upd  = (const int*)d_in[27];

    float* out_ns  = (float*)d_out;
    float* out_q   = out_ns + (size_t)B_ * D_;
    float* out_mem = out_q + B_;

    u16* ws = (u16*)d_ws;
    size_t o = 0;
    u16* obs_bf  = ws + o; o += (size_t)B_ * 512;
    u16* wmem_bf = ws + o; o += (size_t)M_ * 512;
    u16* w_enc1  = ws + o; o += 262144;
    u16* w_k     = ws + o; o += 262144;   // contiguous with w_v -> fused KV weight
    u16* w_v     = ws + o; o += 262144;
    u16* w_tr2   = ws + o; o += 262144;
    u16* w_qh    = ws + o; o += 65536;
    u16* w_q     = ws + o; o += 262144;
    u16* w_tr1   = ws + o; o += (size_t)512 * 576;
    u16* w_e2t   = ws + o; o += 262144;
    u16* w_wot   = ws + o; o += 262144;
    u16* w_qe    = ws + o; o += 262144;
    u16* w_ae    = ws + o; o += 262144;
    u16* w_co    = ws + o; o += 262144;
    u16* hbuf    = ws + o; o += (size_t)B_ * 512;
    u16* qbuf    = ws + o; o += (size_t)B_ * 512;   // unused since R11 (layout stability)
    u16* KVbuf   = ws + o; o += (size_t)1024 * 1024;
    u16* VTb     = ws + o; o += (size_t)512 * 1024;
    u16* ctx     = ws + o; o += (size_t)B_ * 512;
    u16* h2b     = ws + o; o += (size_t)B_ * 512;
    u16* nsbf    = ws + o; o += (size_t)B_ * 512;
    u16* qhb     = ws + o; o += (size_t)B_ * 128;
    u16* ego64   = ws + o; o += (size_t)B_ * 64;
    float* bkv   = (float*)(ws + o); o += 2048;
    float* bqe   = (float*)(ws + o); o += 1024;
    float* btr   = (float*)(ws + o); o += 1024;
    int* list    = (int*)(ws + o);
    int* cnt     = list + B_;
    (void)qbuf;

    const dim3 blk(256);

    prep_all<<<dim3(576, 14), blk, 0, stream>>>(
        enc_w1, wk_f, wv_f, tr_w2, q_w1, wq, tr_w1, enc_w2, wo,
        obs, wmem, ego, bk, bvv, bq, enc_b2, tr_b1, bo,
        w_enc1, w_k, w_v, w_tr2, w_qh, w_q, w_tr1, w_e2t, w_wot,
        obs_bf, wmem_bf, ego64, bkv, bqe, btr);

    megagemm<<<dim3(16, 128, 2), blk, 0, stream>>>(
        obs_bf, w_enc1, enc_b1, hbuf, wmem_bf, w_k, bkv, KVbuf, VTb,
        w_q, w_tr1, w_e2t, w_wot, w_qe, w_ae, w_co);

    ln_bf<<<dim3(2048), blk, 0, stream>>>(hbuf, enc_g, enc_be, B_);

    attn_kernel<<<dim3(64, 8), dim3(512), 0, stream>>>(hbuf, w_qe, bqe, KVbuf, VTb, ctx);

    mgemm<true, false><<<dim3(8, 128), blk, 0, stream>>>(
        hbuf, ctx, ego64, 512, 512, 64, w_ae, w_co, w_tr1 + 512, 512, 512, 576,
        512, 1024, btr, 1.f, 1.f, nullptr, h2b, B_, 512, 1088, 512);
    ln_bf<<<dim3(2048), blk, 0, stream>>>(h2b, tr_g, tr_be, B_);

    mgemm<false, true><<<dim3(8, 128), blk, 0, stream>>>(
        h2b, h2b, h2b, 512, 512, 512, w_tr2, w_tr2, w_tr2, 512, 512, 512,
        512, 512, tr_b2, 1.f, 1.f, out_ns, nsbf, B_, 512, 512, 512);

    mgemm<true, false><<<dim3(2, 128), blk, 0, stream>>>(
        nsbf, nsbf, nsbf, 512, 512, 512, w_qh, w_qh, w_qh, 512, 512, 512,
        512, 512, q_b1, 1.f, 1.f, nullptr, qhb, B_, 128, 512, 128);
    quality_bf<<<dim3(2048), blk, 0, stream>>>(qhb, q_w2, q_b2, out_q, B_);

    compact_kernel<<<dim3(1), dim3(1024), 0, stream>>>(out_q, list, cnt);
    update_memory_kernel<<<dim3(M_), dim3(128), 0, stream>>>(
        wmem, out_ns, upd, list, cnt, out_mem);
}

// Round 14
// 252.259 us; speedup vs baseline: 1.0147x; 1.0147x over previous
//
#include <hip/hip_runtime.h>

#define B_ 8192
#define D_ 512
#define M_ 1000
#define H_ 8
#define LOG2E 1.4426950408889634f

typedef unsigned short u16;
typedef __attribute__((ext_vector_type(8))) short bf16x8;
typedef __attribute__((ext_vector_type(4))) float f32x4;

__device__ __forceinline__ float bf2f(u16 u) {
    union { unsigned u; float f; } c; c.u = ((unsigned)u) << 16; return c.f;
}
__device__ __forceinline__ u16 f2bf(float f) {
    union { float f; unsigned u; } c; c.f = f;
    unsigned r = (c.u + 0x7fffu + ((c.u >> 16) & 1u)) >> 16;
    return (u16)r;
}
__device__ __forceinline__ unsigned f2bf_fast_u(float f) {
    union { float f; unsigned u; } c; c.f = f;
    return (c.u + 0x8000u) >> 16;
}
__device__ __forceinline__ float wave_sum(float v) {
#pragma unroll
    for (int off = 32; off > 0; off >>= 1) v += __shfl_xor(v, off);
    return v;
}

// ---------------------------------------------------------------------------
// bf16 MFMA GEMM core (R8-FINAL config: 64x64 tile, BK=64, 2-barrier).
// CLOSED after 4 experiments (R3/R4/R7/R9). LDS passed in (R7 lesson);
// bx/by passed for fused-grid remapping. 4 waves each 32x32.
// VTOUT: cols >= 512 written transposed to VT[(col-512)*1024+row], zero-padded.
// ---------------------------------------------------------------------------
template<bool RELU, bool WF32, bool VTOUT>
__device__ __forceinline__ void gemm_core(
    int bx, int by, u16* As, u16* Bs,
    const u16* __restrict__ A0, const u16* __restrict__ A1,
    const u16* __restrict__ A2, int lda0, int lda1, int lda2,
    const u16* __restrict__ W0, const u16* __restrict__ W1,
    const u16* __restrict__ W2, int ldw0, int ldw1, int ldw2,
    int kb1, int kb2,
    const float* __restrict__ bias, float bscale, float cscale,
    float* __restrict__ Cf, u16* __restrict__ Cb, u16* __restrict__ VT,
    int M, int N, int K, int ldc)
{
    const int m0 = by * 64, n0 = bx * 64;
    if (m0 >= M || n0 >= N) return;
    const int t = threadIdx.x, w = t >> 6, l = t & 63;
    const int wm = (w >> 1) * 32, wn = (w & 1) * 32;
    const int li = l & 15, quad = l >> 4;

    f32x4 acc[2][2];
#pragma unroll
    for (int i = 0; i < 2; ++i)
#pragma unroll
        for (int j = 0; j < 2; ++j) acc[i][j] = (f32x4){0.f, 0.f, 0.f, 0.f};

    for (int k0 = 0; k0 < K; k0 += 64) {
        const u16* Ab; const u16* Wb; int ldab, ldwb, ko;
        if (k0 < kb1)      { Ab = A0; ldab = lda0; Wb = W0; ldwb = ldw0; ko = k0; }
        else if (k0 < kb2) { Ab = A1; ldab = lda1; Wb = W1; ldwb = ldw1; ko = k0 - kb1; }
        else               { Ab = A2; ldab = lda2; Wb = W2; ldwb = ldw2; ko = k0 - kb2; }
#pragma unroll
        for (int i = 0; i < 2; ++i) {
            const int rl = w * 16 + i * 8 + (l >> 3);
            const int ck = (l & 7) ^ (rl & 7);
            int ga = m0 + rl; ga = ga < M ? ga : M - 1;
            __builtin_amdgcn_global_load_lds(
                (const __attribute__((address_space(1))) void*)(Ab + (size_t)ga * ldab + ko + ck * 8),
                (__attribute__((address_space(3))) void*)(As + (w * 16 + i * 8) * 64),
                16, 0, 0);
        }
#pragma unroll
        for (int i = 0; i < 2; ++i) {
            const int rl = w * 16 + i * 8 + (l >> 3);
            const int ck = (l & 7) ^ (rl & 7);
            int gb = n0 + rl; gb = gb < N ? gb : N - 1;
            __builtin_amdgcn_global_load_lds(
                (const __attribute__((address_space(1))) void*)(Wb + (size_t)gb * ldwb + ko + ck * 8),
                (__attribute__((address_space(3))) void*)(Bs + (w * 16 + i * 8) * 64),
                16, 0, 0);
        }
        __syncthreads();
#pragma unroll
        for (int ks = 0; ks < 2; ++ks) {
            const int ch = ks * 4 + quad;
            bf16x8 af[2], bfr[2];
#pragma unroll
            for (int mt = 0; mt < 2; ++mt) {
                const int r = wm + mt * 16 + li;
                af[mt] = *(const bf16x8*)(As + r * 64 + ((ch ^ (r & 7)) * 8));
            }
#pragma unroll
            for (int nt = 0; nt < 2; ++nt) {
                const int r = wn + nt * 16 + li;
                bfr[nt] = *(const bf16x8*)(Bs + r * 64 + ((ch ^ (r & 7)) * 8));
            }
#pragma unroll
            for (int mt = 0; mt < 2; ++mt)
#pragma unroll
                for (int nt = 0; nt < 2; ++nt)
                    acc[mt][nt] = __builtin_amdgcn_mfma_f32_16x16x32_bf16(
                        af[mt], bfr[nt], acc[mt][nt], 0, 0, 0);
        }
        __syncthreads();
    }

    float bv[2];
#pragma unroll
    for (int nt = 0; nt < 2; ++nt) bv[nt] = bias[n0 + wn + nt * 16 + li] * bscale;
#pragma unroll
    for (int mt = 0; mt < 2; ++mt) {
        const int row0 = m0 + wm + mt * 16 + quad * 4;
#pragma unroll
        for (int nt = 0; nt < 2; ++nt) {
            const int col = n0 + wn + nt * 16 + li;
            if (VTOUT && col >= 512) {
                ushort4 pk;
                u16 pv[4];
#pragma unroll
                for (int r = 0; r < 4; ++r) {
                    float v = acc[mt][nt][r] * cscale + bv[nt];
                    pv[r] = (row0 + r < M_) ? f2bf(v) : (u16)0;
                }
                pk.x = pv[0]; pk.y = pv[1]; pk.z = pv[2]; pk.w = pv[3];
                *(ushort4*)(VT + (size_t)(col - 512) * 1024 + row0) = pk;
            } else {
#pragma unroll
                for (int r = 0; r < 4; ++r) {
                    const int row = row0 + r;
                    if (row >= M) continue;
                    float v = acc[mt][nt][r] * cscale + bv[nt];
                    if (RELU) v = fmaxf(v, 0.f);
                    Cb[(size_t)row * ldc + col] = f2bf(v);
                    if (WF32) Cf[(size_t)row * ldc + col] = v;
                }
            }
        }
    }
}

template<bool RELU, bool WF32>
__launch_bounds__(256)
__global__ void mgemm(const u16* __restrict__ A0, const u16* __restrict__ A1,
                      const u16* __restrict__ A2, int lda0, int lda1, int lda2,
                      const u16* __restrict__ W0, const u16* __restrict__ W1,
                      const u16* __restrict__ W2, int ldw0, int ldw1, int ldw2,
                      int kb1, int kb2,
                      const float* __restrict__ bias, float bscale, float cscale,
                      float* __restrict__ Cf, u16* __restrict__ Cb,
                      int M, int N, int K, int ldc)
{
    __shared__ u16 As[64 * 64];
    __shared__ u16 Bs[64 * 64];
    gemm_core<RELU, WF32, false>(blockIdx.x, blockIdx.y, As, Bs,
                                 A0, A1, A2, lda0, lda1, lda2,
                                 W0, W1, W2, ldw0, ldw1, ldw2, kb1, kb2,
                                 bias, bscale, cscale, Cf, Cb, nullptr, M, N, K, ldc);
}

// ---------------------------------------------------------------------------
// enc + KV-projection + 3 weight-folds fused in ONE dispatch (single
// kernel-scope LDS). Grid (16,128,2): z=0 enc; z=1: KV + 3 folds.
// ---------------------------------------------------------------------------
__launch_bounds__(256)
__global__ void megagemm(const u16* __restrict__ obs_bf, const u16* __restrict__ w_enc1,
                         const float* __restrict__ enc_b1, u16* __restrict__ hbuf,
                         const u16* __restrict__ wmem_bf, const u16* __restrict__ w_k,
                         const float* __restrict__ bkv, u16* __restrict__ KVbuf,
                         u16* __restrict__ VTb,
                         const u16* __restrict__ w_q, const u16* __restrict__ w_tr1,
                         const u16* __restrict__ w_e2t, const u16* __restrict__ w_wot,
                         u16* __restrict__ w_qe, u16* __restrict__ w_ae,
                         u16* __restrict__ w_co)
{
    __shared__ u16 As[64 * 64];
    __shared__ u16 Bs[64 * 64];
    const int bx = blockIdx.x, by = blockIdx.y;
    if (blockIdx.z == 0) {
        gemm_core<true, false, false>(bx, by, As, Bs,
            obs_bf, obs_bf, obs_bf, 512, 512, 512,
            w_enc1, w_enc1, w_enc1, 512, 512, 512, 512, 512,
            enc_b1, 1.f, 1.f, nullptr, hbuf, nullptr, B_, 512, 512, 512);
    } else {
        if (by < 16) {
            gemm_core<false, false, true>(bx, by, As, Bs,
                wmem_bf, wmem_bf, wmem_bf, 512, 512, 512,
                w_k, w_k, w_k, 512, 512, 512, 512, 512,
                bkv, 1.f, 1.f, nullptr, KVbuf, VTb, 1024, 1024, 512, 1024);
        } else if (by < 24) {
            gemm_core<false, false, false>(bx, by - 16, As, Bs,
                w_q, w_q, w_q, 512, 512, 512,
                w_e2t, w_e2t, w_e2t, 512, 512, 512, 512, 512,
                bkv, 0.f, 1.0f, nullptr, w_qe, nullptr, 512, 512, 512, 512);
        } else if (by < 32) {
            gemm_core<false, false, false>(bx, by - 24, As, Bs,
                w_tr1, w_tr1, w_tr1, 576, 576, 576,
                w_e2t, w_e2t, w_e2t, 512, 512, 512, 512, 512,
                bkv, 0.f, 0.7f, nullptr, w_ae, nullptr, 512, 512, 512, 512);
        } else if (by < 40) {
            gemm_core<false, false, false>(bx, by - 32, As, Bs,
                w_tr1, w_tr1, w_tr1, 576, 576, 576,
                w_wot, w_wot, w_wot, 512, 512, 512, 512, 512,
                bkv, 0.f, 0.3f, nullptr, w_co, nullptr, 512, 512, 512, 512);
        }
    }
}

// ---------------------------------------------------------------------------
// R14: quality head FUSED: one kernel computes qh = relu(nsbf@w_qh^T + b1)
// for a 64x128 tile AND reduces sigmoid(qh.w2 + b2) in-epilogue.
// Replaces the quality mgemm + quality_bf pair (-1 dispatch, -4MB qhb
// round-trip). Reduction: per-thread partial dot over its 4 cols x 8 rows,
// shfl_xor over the 16-lane li group, cross-wave halves via 512B LDS.
// f32 accumulation end-to-end (closer to reference than the bf16 qhb path).
// ---------------------------------------------------------------------------
__launch_bounds__(256)
__global__ void quality_fused(const u16* __restrict__ A,     // nsbf [B_][512]
                              const u16* __restrict__ Wq,    // w_qh [128][512]
                              const float* __restrict__ b1,  // [128]
                              const float* __restrict__ w2,  // [128]
                              const float* __restrict__ b2,  // [1]
                              float* __restrict__ outq)      // [B_]
{
    __shared__ u16 As[64 * 64];
    __shared__ u16 Bs[128 * 64];
    __shared__ float halves[64][2];
    const int m0 = blockIdx.x * 64;
    const int t = threadIdx.x, w = t >> 6, l = t & 63;
    const int wm = (w >> 1) * 32, wn = (w & 1) * 64;
    const int li = l & 15, quad = l >> 4;

    f32x4 acc[2][4];
#pragma unroll
    for (int i = 0; i < 2; ++i)
#pragma unroll
        for (int j = 0; j < 4; ++j) acc[i][j] = (f32x4){0.f, 0.f, 0.f, 0.f};

    for (int k0 = 0; k0 < 512; k0 += 64) {
#pragma unroll
        for (int i = 0; i < 2; ++i) {
            const int rl = w * 16 + i * 8 + (l >> 3);
            const int ck = (l & 7) ^ (rl & 7);
            __builtin_amdgcn_global_load_lds(
                (const __attribute__((address_space(1))) void*)(A + (size_t)(m0 + rl) * 512 + k0 + ck * 8),
                (__attribute__((address_space(3))) void*)(As + (w * 16 + i * 8) * 64),
                16, 0, 0);
        }
#pragma unroll
        for (int i = 0; i < 4; ++i) {
            const int f = i * 256 + t;
            const int rl = f >> 3;                 // 0..127
            const int ck = (f & 7) ^ (rl & 7);
            __builtin_amdgcn_global_load_lds(
                (const __attribute__((address_space(1))) void*)(Wq + (size_t)rl * 512 + k0 + ck * 8),
                (__attribute__((address_space(3))) void*)(Bs + (i * 256 + w * 64) * 8),
                16, 0, 0);
        }
        __syncthreads();
#pragma unroll
        for (int ks = 0; ks < 2; ++ks) {
            const int ch = ks * 4 + quad;
            bf16x8 af[2], bfr[4];
#pragma unroll
            for (int mt = 0; mt < 2; ++mt) {
                const int r = wm + mt * 16 + li;
                af[mt] = *(const bf16x8*)(As + r * 64 + ((ch ^ (r & 7)) * 8));
            }
#pragma unroll
            for (int nt = 0; nt < 4; ++nt) {
                const int r = wn + nt * 16 + li;
                bfr[nt] = *(const bf16x8*)(Bs + r * 64 + ((ch ^ (r & 7)) * 8));
            }
#pragma unroll
            for (int mt = 0; mt < 2; ++mt)
#pragma unroll
                for (int nt = 0; nt < 4; ++nt)
                    acc[mt][nt] = __builtin_amdgcn_mfma_f32_16x16x32_bf16(
                        af[mt], bfr[nt], acc[mt][nt], 0, 0, 0);
        }
        __syncthreads();
    }

    // per-thread partial dot: rows wm+mt*16+quad*4+r, cols wn+nt*16+li
    float part[2][4];
#pragma unroll
    for (int mt = 0; mt < 2; ++mt)
#pragma unroll
        for (int r = 0; r < 4; ++r) part[mt][r] = 0.f;
#pragma unroll
    for (int nt = 0; nt < 4; ++nt) {
        const int col = wn + nt * 16 + li;
        const float wv = w2[col];
        const float bb = b1[col];
#pragma unroll
        for (int mt = 0; mt < 2; ++mt)
#pragma unroll
            for (int r = 0; r < 4; ++r)
                part[mt][r] += fmaxf(acc[mt][nt][r] + bb, 0.f) * wv;
    }
#pragma unroll
    for (int off = 1; off < 16; off <<= 1)
#pragma unroll
        for (int mt = 0; mt < 2; ++mt)
#pragma unroll
            for (int r = 0; r < 4; ++r)
                part[mt][r] += __shfl_xor(part[mt][r], off);
    if (li == 0) {
#pragma unroll
        for (int mt = 0; mt < 2; ++mt)
#pragma unroll
            for (int r = 0; r < 4; ++r)
                halves[wm + mt * 16 + quad * 4 + r][w & 1] = part[mt][r];
    }
    __syncthreads();
    if (t < 64) {
        const float s = halves[t][0] + halves[t][1] + b2[0];
        outq[m0 + t] = 1.0f / (1.0f + expf(-s));
    }
}

// ---------------------------------------------------------------------------
// Fused flash attention (R13: 8-wave blocks, 16 q-rows/wave, XOR-swizzled P,
// packed b64 P writes, Q-projection prologue, T5 setprio).
// ---------------------------------------------------------------------------
__launch_bounds__(512, 2)
__global__ void attn_kernel(const u16* __restrict__ hn, const u16* __restrict__ w_qe,
                            const float* __restrict__ bqe,
                            const u16* __restrict__ KV,
                            const u16* __restrict__ VT, u16* __restrict__ ctx)
{
    __shared__ u16 Ks[2][64 * 64];
    __shared__ u16 Vs[2][64 * 64];
    __shared__ u16 P[128 * 64];
    const int t = threadIdx.x, w = t >> 6, l = t & 63;
    const int h = blockIdx.y;
    const int q0b = blockIdx.x * 128;
    u16* Pw = P + w * 1024;
    const int li = l & 15, quad = l >> 4;

    auto stage = [&](int kc, int buf) {
        {
            const int r = t >> 3;
            const int ck = (t & 7) ^ (r & 7);
            __builtin_amdgcn_global_load_lds(
                (const __attribute__((address_space(1))) void*)(KV + (size_t)(kc + r) * 1024 + h * 64 + ck * 8),
                (__attribute__((address_space(3))) void*)(&Ks[buf][t * 8]),
                16, 0, 0);
        }
        {
            const int r = t >> 3;
            const int ck = (t & 7) ^ (r & 7);
            __builtin_amdgcn_global_load_lds(
                (const __attribute__((address_space(1))) void*)(VT + (size_t)(h * 64 + r) * 1024 + kc + ck * 8),
                (__attribute__((address_space(3))) void*)(&Vs[buf][t * 8]),
                16, 0, 0);
        }
    };

    // ---- Q-projection prologue
    {
        u16* Ksf = &Ks[0][0];
        u16* Bsf = &Vs[0][0];
        f32x4 qacc[4];
#pragma unroll
        for (int nt = 0; nt < 4; ++nt) qacc[nt] = (f32x4){0.f, 0.f, 0.f, 0.f};

        for (int k0 = 0; k0 < 512; k0 += 64) {
#pragma unroll
            for (int i = 0; i < 2; ++i) {
                const int f = i * 512 + t;
                const int rl = f >> 3;
                const int ck = (f & 7) ^ (rl & 7);
                __builtin_amdgcn_global_load_lds(
                    (const __attribute__((address_space(1))) void*)(hn + (size_t)(q0b + rl) * 512 + k0 + ck * 8),
                    (__attribute__((address_space(3))) void*)(Ksf + f * 8),
                    16, 0, 0);
            }
            {
                const int rl = t >> 3;
                const int ck = (t & 7) ^ (rl & 7);
                __builtin_amdgcn_global_load_lds(
                    (const __attribute__((address_space(1))) void*)(w_qe + (size_t)(h * 64 + rl) * 512 + k0 + ck * 8),
                    (__attribute__((address_space(3))) void*)(Bsf + t * 8),
                    16, 0, 0);
            }
            __syncthreads();
            __builtin_amdgcn_s_setprio(1);
#pragma unroll
            for (int ks = 0; ks < 2; ++ks) {
                const int ch = ks * 4 + quad;
                const int r = w * 16 + li;
                const bf16x8 af = *(const bf16x8*)(Ksf + r * 64 + ((ch ^ (r & 7)) * 8));
                bf16x8 bfr[4];
#pragma unroll
                for (int nt = 0; nt < 4; ++nt) {
                    const int rb = nt * 16 + li;
                    bfr[nt] = *(const bf16x8*)(Bsf + rb * 64 + ((ch ^ (rb & 7)) * 8));
                }
#pragma unroll
                for (int nt = 0; nt < 4; ++nt)
                    qacc[nt] = __builtin_amdgcn_mfma_f32_16x16x32_bf16(
                        af, bfr[nt], qacc[nt], 0, 0, 0);
            }
            __builtin_amdgcn_s_setprio(0);
            __syncthreads();
        }

        stage(0, 0);

#pragma unroll
        for (int nt = 0; nt < 4; ++nt) {
            const int col = nt * 16 + li;
            const float bv = bqe[h * 64 + col];
#pragma unroll
            for (int r = 0; r < 4; ++r) {
                const int row = w * 16 + quad * 4 + r;
                P[row * 64 + (((2 * nt + (li >> 3)) ^ (row & 7)) * 8) + (li & 7)] =
                    f2bf(qacc[nt][r] + bv);
            }
        }
    }

    bf16x8 aq[2];
#pragma unroll
    for (int ks = 0; ks < 2; ++ks) {
        const int row = w * 16 + li;
        aq[ks] = *(const bf16x8*)(P + row * 64 + (((ks * 4 + quad) ^ (li & 7)) * 8));
    }

    bf16x8 ones;
#pragma unroll
    for (int i = 0; i < 8; ++i) ones[i] = (short)0x3F80;

    f32x4 oacc[4];
    f32x4 lacc = (f32x4){0.f, 0.f, 0.f, 0.f};
#pragma unroll
    for (int nt = 0; nt < 4; ++nt) oacc[nt] = (f32x4){0.f, 0.f, 0.f, 0.f};

    for (int ic = 0; ic < 16; ++ic) {
        const int kc = ic * 64;
        __syncthreads();
        if (ic < 15) stage(kc + 64, (ic + 1) & 1);
        const u16* ksb = &Ks[ic & 1][0];
        const u16* vsb = &Vs[ic & 1][0];

        f32x4 s[4];
#pragma unroll
        for (int kmt = 0; kmt < 4; ++kmt) s[kmt] = (f32x4){0.f, 0.f, 0.f, 0.f};
        __builtin_amdgcn_s_setprio(1);
#pragma unroll
        for (int ks = 0; ks < 2; ++ks) {
            const int ch = ks * 4 + quad;
            bf16x8 bk[4];
#pragma unroll
            for (int kmt = 0; kmt < 4; ++kmt) {
                const int key = kmt * 16 + li;
                bk[kmt] = *(const bf16x8*)(ksb + key * 64 + ((ch ^ (key & 7)) * 8));
            }
#pragma unroll
            for (int kmt = 0; kmt < 4; ++kmt)
                s[kmt] = __builtin_amdgcn_mfma_f32_16x16x32_bf16(
                    bk[kmt], aq[ks], s[kmt], 0, 0, 0);
        }
        __builtin_amdgcn_s_setprio(0);
        if (kc == 960) {
#pragma unroll
            for (int kmt = 2; kmt < 4; ++kmt)
#pragma unroll
                for (int r = 0; r < 4; ++r) {
                    const int key_local = kmt * 16 + quad * 4 + r;
                    if (960 + key_local >= M_) s[kmt][r] = -3.0e38f;
                }
        }
#pragma unroll
        for (int kmt = 0; kmt < 4; ++kmt) {
            const unsigned b0 = f2bf_fast_u(exp2f(s[kmt][0]));
            const unsigned b1 = f2bf_fast_u(exp2f(s[kmt][1]));
            const unsigned b2w = f2bf_fast_u(exp2f(s[kmt][2]));
            const unsigned b3 = f2bf_fast_u(exp2f(s[kmt][3]));
            const int chunk = (2 * kmt + (quad >> 1)) ^ (li & 7);
            const int off = li * 64 + chunk * 8 + (quad & 1) * 4;
            *(uint2*)(Pw + off) = make_uint2(b0 | (b1 << 16), b2w | (b3 << 16));
        }
        __builtin_amdgcn_s_setprio(1);
#pragma unroll
        for (int ks = 0; ks < 2; ++ks) {
            const int ch = ks * 4 + quad;
            const bf16x8 ap = *(const bf16x8*)(Pw + li * 64 + ((ch ^ (li & 7)) * 8));
            lacc = __builtin_amdgcn_mfma_f32_16x16x32_bf16(ap, ones, lacc, 0, 0, 0);
#pragma unroll
            for (int nt = 0; nt < 4; ++nt) {
                const int dh = nt * 16 + li;
                const bf16x8 bvv = *(const bf16x8*)(vsb + dh * 64 + ((ch ^ (dh & 7)) * 8));
                oacc[nt] = __builtin_amdgcn_mfma_f32_16x16x32_bf16(
                    ap, bvv, oacc[nt], 0, 0, 0);
            }
        }
        __builtin_amdgcn_s_setprio(0);
    }

#pragma unroll
    for (int r = 0; r < 4; ++r) {
        const int row = q0b + w * 16 + quad * 4 + r;
        const float inv = 1.0f / lacc[r];
#pragma unroll
        for (int nt = 0; nt < 4; ++nt)
            ctx[(size_t)row * 512 + h * 64 + nt * 16 + li] = f2bf(oacc[nt][r] * inv);
    }
}

__launch_bounds__(256)
__global__ void ln_bf(u16* __restrict__ X, const float* __restrict__ g,
                      const float* __restrict__ be, int rows)
{
    const int row = blockIdx.x * 4 + (threadIdx.x >> 6);
    const int lane = threadIdx.x & 63;
    if (row >= rows) return;
    u16* p = X + (size_t)row * 512 + lane * 8;
    uint4 d = *(const uint4*)p;
    const unsigned dd[4] = {d.x, d.y, d.z, d.w};
    float v[8];
#pragma unroll
    for (int i = 0; i < 4; ++i) {
        v[2 * i]     = bf2f((u16)(dd[i] & 0xffffu));
        v[2 * i + 1] = bf2f((u16)(dd[i] >> 16));
    }
    float s = 0.f;
#pragma unroll
    for (int i = 0; i < 8; ++i) s += v[i];
    s = wave_sum(s);
    const float mu = s * (1.0f / 512.0f);
    float vs = 0.f;
#pragma unroll
    for (int i = 0; i < 8; ++i) { v[i] -= mu; vs += v[i] * v[i]; }
    vs = wave_sum(vs);
    const float r = rsqrtf(vs * (1.0f / 512.0f) + 1e-5f);
    const float* gp = g + lane * 8;
    const float* bp = be + lane * 8;
    unsigned o[4];
#pragma unroll
    for (int i = 0; i < 4; ++i) {
        const u16 lo = f2bf(v[2 * i] * r * gp[2 * i] + bp[2 * i]);
        const u16 hi = f2bf(v[2 * i + 1] * r * gp[2 * i + 1] + bp[2 * i + 1]);
        o[i] = (unsigned)lo | ((unsigned)hi << 16);
    }
    *(uint4*)p = make_uint4(o[0], o[1], o[2], o[3]);
}

// one-dispatch prep: weight converts (0-6), transposes (7-8), activation
// converts (9-11), bias folds (12-13)  (R6-exact)
__launch_bounds__(256)
__global__ void prep_all(const float* enc_w1, const float* wk_f, const float* wv_f,
                         const float* tr_w2, const float* q_w1, const float* wq,
                         const float* tr_w1, const float* enc_w2, const float* wo,
                         const float* obs, const float* wmem, const float* ego,
                         const float* bk, const float* bvv, const float* bq,
                         const float* enc_b2, const float* trb1, const float* bo,
                         u16* w_enc1, u16* w_k, u16* w_v, u16* w_tr2, u16* w_qh,
                         u16* w_q, u16* w_tr1, u16* w_e2t, u16* w_wot,
                         u16* obs_bf, u16* wmem_bf, u16* ego64,
                         float* bkv, float* bqe, float* btr)
{
    __shared__ float tl[64][65];
    const int seg = blockIdx.y;
    const int t = threadIdx.x;
    const int bx = blockIdx.x;

    if (seg <= 5) {
        const float* s; u16* d; int n; float sc = 1.0f;
        switch (seg) {
            case 0: s = enc_w1; d = w_enc1; n = 262144; break;
            case 1: s = wk_f;   d = w_k;    n = 262144; break;
            case 2: s = wv_f;   d = w_v;    n = 262144; break;
            case 3: s = tr_w2;  d = w_tr2;  n = 262144; break;
            case 4: s = q_w1;   d = w_qh;   n = 65536;  break;
            default: s = wq;    d = w_q;    n = 262144; sc = 0.125f * LOG2E; break;
        }
        const int i0 = (bx * 256 + t) * 4;
        if (i0 + 3 < n) {
            const float4 v = *(const float4*)(s + i0);
            ushort4 o;
            o.x = f2bf(v.x * sc); o.y = f2bf(v.y * sc);
            o.z = f2bf(v.z * sc); o.w = f2bf(v.w * sc);
            *(ushort4*)(d + i0) = o;
        }
    } else if (seg == 6) {
#pragma unroll
        for (int k = 0; k < 4; ++k) {
            const int i = (bx * 256 + t) * 4 + k;
            if (i < 294912) {
                const int r = i / 576, c = i - r * 576;
                w_tr1[i] = (c < 528) ? f2bf(tr_w1[r * 528 + c]) : (u16)0;
            }
        }
    } else if (seg <= 8) {
        if (bx >= 64) return;
        const float* S = (seg == 7) ? enc_w2 : wo;
        u16* D = (seg == 7) ? w_e2t : w_wot;
        const int r0 = (bx >> 3) * 64, c0 = (bx & 7) * 64;
#pragma unroll
        for (int i = 0; i < 16; ++i) {
            const int idx = t + i * 256;
            tl[idx >> 6][idx & 63] = S[(size_t)(r0 + (idx >> 6)) * 512 + c0 + (idx & 63)];
        }
        __syncthreads();
#pragma unroll
        for (int i = 0; i < 16; ++i) {
            const int idx = t + i * 256;
            const int c = idx >> 6, r = idx & 63;
            D[(size_t)(c0 + c) * 512 + r0 + r] = f2bf(tl[r][c]);
        }
    } else if (seg == 9) {
        const int nth = gridDim.x * 256;
        for (int i = bx * 256 + t; i < B_ * 512 / 4; i += nth) {
            const float4 v = ((const float4*)obs)[i];
            ushort4 o;
            o.x = f2bf(v.x); o.y = f2bf(v.y); o.z = f2bf(v.z); o.w = f2bf(v.w);
            ((ushort4*)obs_bf)[i] = o;
        }
    } else if (seg == 10) {
        const int nth = gridDim.x * 256;
        for (int i = bx * 256 + t; i < M_ * 512 / 4; i += nth) {
            const float4 v = ((const float4*)wmem)[i];
            ushort4 o;
            o.x = f2bf(v.x); o.y = f2bf(v.y); o.z = f2bf(v.z); o.w = f2bf(v.w);
            ((ushort4*)wmem_bf)[i] = o;
        }
    } else if (seg == 11) {
        const int nth = gridDim.x * 256;
        for (int i = bx * 256 + t; i < B_ * 64; i += nth) {
            const int b = i >> 6, j = i & 63;
            ego64[(size_t)b * 64 + j] = (j < 16) ? f2bf(ego[b * 16 + j]) : (u16)0;
        }
        const int tid = bx * 256 + t;
        if (tid < 1024) bkv[tid] = (tid < 512) ? bk[tid] : bvv[tid - 512];
    } else {
        if (bx >= 128) return;
        const int i = bx * 4 + (t >> 6);
        const int lane = t & 63;
        float s = 0.f;
        if (seg == 12) {
            const float* wr = wq + (size_t)i * 512 + lane * 8;
#pragma unroll
            for (int j = 0; j < 8; ++j) s += wr[j] * enc_b2[lane * 8 + j];
            s = wave_sum(s);
            if (lane == 0) bqe[i] = 0.125f * LOG2E * (bq[i] + s);
        } else {
            const float* wr = tr_w1 + (size_t)i * 528 + lane * 8;
#pragma unroll
            for (int j = 0; j < 8; ++j)
                s += wr[j] * (0.7f * enc_b2[lane * 8 + j] + 0.3f * bo[lane * 8 + j]);
            s = wave_sum(s);
            if (lane == 0) btr[i] = trb1[i] + s;
        }
    }
}

__global__ void compact_kernel(const float* __restrict__ q,
                               int* __restrict__ list, int* __restrict__ cnt)
{
    __shared__ int wtot[16];
    __shared__ int sbase;
    const int t = threadIdx.x, w = t >> 6, lane = t & 63;
    if (t == 0) sbase = 0;
    __syncthreads();
    for (int c = 0; c < B_; c += 1024) {
        const int idx = c + t;
        const bool pred = (q[idx] > 0.7f);
        const unsigned long long bal = __ballot(pred);
        const int prefix = __popcll(bal & ((1ull << lane) - 1ull));
        if (lane == 0) wtot[w] = __popcll(bal);
        __syncthreads();
        int woff = 0;
        for (int i = 0; i < w; ++i) woff += wtot[i];
        if (pred) list[sbase + woff + prefix] = idx;
        __syncthreads();
        if (t == 0) {
            int tot = 0;
            for (int i = 0; i < 16; ++i) tot += wtot[i];
            sbase += tot;
        }
        __syncthreads();
    }
    if (t == 0) *cnt = sbase;
}

__global__ void update_memory_kernel(const float* __restrict__ mem,
                                     const float* __restrict__ ns,
                                     const int* __restrict__ upd,
                                     const int* __restrict__ list,
                                     const int* __restrict__ cnt,
                                     float* __restrict__ outmem)
{
    const int m = blockIdx.x;
    const int t = threadIdx.x;
    const int c4 = t * 4;
    float4 r = *(const float4*)(mem + (size_t)m * D_ + c4);
    const int n = *cnt;
    for (int i = 0; i < n; ++i) {
        const int b = list[i];
        if (upd[b] == m) {
            const float4 s = *(const float4*)(ns + (size_t)b * D_ + c4);
            r.x = 0.9f * r.x + 0.1f * s.x;
            r.y = 0.9f * r.y + 0.1f * s.y;
            r.z = 0.9f * r.z + 0.1f * s.z;
            r.w = 0.9f * r.w + 0.1f * s.w;
        }
    }
    *(float4*)(outmem + (size_t)m * D_ + c4) = r;
}

extern "C" void kernel_launch(void* const* d_in, const int* in_sizes, int n_in,
                              void* d_out, int out_size, void* d_ws, size_t ws_size,
                              hipStream_t stream)
{
    const float* obs    = (const float*)d_in[0];
    const float* ego    = (const float*)d_in[1];
    const float* wmem   = (const float*)d_in[2];
    const float* enc_w1 = (const float*)d_in[3];
    const float* enc_b1 = (const float*)d_in[4];
    const float* enc_g  = (const float*)d_in[5];
    const float* enc_be = (const float*)d_in[6];
    const float* enc_w2 = (const float*)d_in[7];
    const float* enc_b2 = (const float*)d_in[8];
    const float* wq = (const float*)d_in[9];
    const float* bq = (const float*)d_in[10];
    const float* wk_f = (const float*)d_in[11];
    const float* bk = (const float*)d_in[12];
    const float* wv_f = (const float*)d_in[13];
    const float* bvv = (const float*)d_in[14];
    const float* wo = (const float*)d_in[15];
    const float* bo = (const float*)d_in[16];
    const float* tr_w1 = (const float*)d_in[17];
    const float* tr_b1 = (const float*)d_in[18];
    const float* tr_g  = (const float*)d_in[19];
    const float* tr_be = (const float*)d_in[20];
    const float* tr_w2 = (const float*)d_in[21];
    const float* tr_b2 = (const float*)d_in[22];
    const float* q_w1 = (const float*)d_in[23];
    const float* q_b1 = (const float*)d_in[24];
    const float* q_w2 = (const float*)d_in[25];
    const float* q_b2 = (const float*)d_in[26];
    const int*   upd  = (const int*)d_in[27];

    float* out_ns  = (float*)d_out;
    float* out_q   = out_ns + (size_t)B_ * D_;
    float* out_mem = out_q + B_;

    u16* ws = (u16*)d_ws;
    size_t o = 0;
    u16* obs_bf  = ws + o; o += (size_t)B_ * 512;
    u16* wmem_bf = ws + o; o += (size_t)M_ * 512;
    u16* w_enc1  = ws + o; o += 262144;
    u16* w_k     = ws + o; o += 262144;   // contiguous with w_v -> fused KV weight
    u16* w_v     = ws + o; o += 262144;
    u16* w_tr2   = ws + o; o += 262144;
    u16* w_qh    = ws + o; o += 65536;
    u16* w_q     = ws + o; o += 262144;
    u16* w_tr1   = ws + o; o += (size_t)512 * 576;
    u16* w_e2t   = ws + o; o += 262144;
    u16* w_wot   = ws + o; o += 262144;
    u16* w_qe    = ws + o; o += 262144;
    u16* w_ae    = ws + o; o += 262144;
    u16* w_co    = ws + o; o += 262144;
    u16* hbuf    = ws + o; o += (size_t)B_ * 512;
    u16* qbuf    = ws + o; o += (size_t)B_ * 512;   // unused since R11 (layout stability)
    u16* KVbuf   = ws + o; o += (size_t)1024 * 1024;
    u16* VTb     = ws + o; o += (size_t)512 * 1024;
    u16* ctx     = ws + o; o += (size_t)B_ * 512;
    u16* h2b     = ws + o; o += (size_t)B_ * 512;
    u16* nsbf    = ws + o; o += (size_t)B_ * 512;
    u16* qhb     = ws + o; o += (size_t)B_ * 128;   // unused since R14
    u16* ego64   = ws + o; o += (size_t)B_ * 64;
    float* bkv   = (float*)(ws + o); o += 2048;
    float* bqe   = (float*)(ws + o); o += 1024;
    float* btr   = (float*)(ws + o); o += 1024;
    int* list    = (int*)(ws + o);
    int* cnt     = list + B_;
    (void)qbuf; (void)qhb;

    const dim3 blk(256);

    prep_all<<<dim3(576, 14), blk, 0, stream>>>(
        enc_w1, wk_f, wv_f, tr_w2, q_w1, wq, tr_w1, enc_w2, wo,
        obs, wmem, ego, bk, bvv, bq, enc_b2, tr_b1, bo,
        w_enc1, w_k, w_v, w_tr2, w_qh, w_q, w_tr1, w_e2t, w_wot,
        obs_bf, wmem_bf, ego64, bkv, bqe, btr);

    megagemm<<<dim3(16, 128, 2), blk, 0, stream>>>(
        obs_bf, w_enc1, enc_b1, hbuf, wmem_bf, w_k, bkv, KVbuf, VTb,
        w_q, w_tr1, w_e2t, w_wot, w_qe, w_ae, w_co);

    ln_bf<<<dim3(2048), blk, 0, stream>>>(hbuf, enc_g, enc_be, B_);

    attn_kernel<<<dim3(64, 8), dim3(512), 0, stream>>>(hbuf, w_qe, bqe, KVbuf, VTb, ctx);

    mgemm<true, false><<<dim3(8, 128), blk, 0, stream>>>(
        hbuf, ctx, ego64, 512, 512, 64, w_ae, w_co, w_tr1 + 512, 512, 512, 576,
        512, 1024, btr, 1.f, 1.f, nullptr, h2b, B_, 512, 1088, 512);
    ln_bf<<<dim3(2048), blk, 0, stream>>>(h2b, tr_g, tr_be, B_);

    mgemm<false, true><<<dim3(8, 128), blk, 0, stream>>>(
        h2b, h2b, h2b, 512, 512, 512, w_tr2, w_tr2, w_tr2, 512, 512, 512,
        512, 512, tr_b2, 1.f, 1.f, out_ns, nsbf, B_, 512, 512, 512);

    quality_fused<<<dim3(128), blk, 0, stream>>>(nsbf, w_qh, q_b1, q_w2, q_b2, out_q);

    compact_kernel<<<dim3(1), dim3(1024), 0, stream>>>(out_q, list, cnt);
    update_memory_kernel<<<dim3(M_), dim3(128), 0, stream>>>(
        wmem, out_ns, upd, list, cnt, out_mem);
}

// Round 15
// 246.237 us; speedup vs baseline: 1.0396x; 1.0245x over previous
//
#include <hip/hip_runtime.h>

#define B_ 8192
#define D_ 512
#define M_ 1000
#define H_ 8
#define LOG2E 1.4426950408889634f

typedef unsigned short u16;
typedef __attribute__((ext_vector_type(8))) short bf16x8;
typedef __attribute__((ext_vector_type(4))) float f32x4;

__device__ __forceinline__ float bf2f(u16 u) {
    union { unsigned u; float f; } c; c.u = ((unsigned)u) << 16; return c.f;
}
__device__ __forceinline__ u16 f2bf(float f) {
    union { float f; unsigned u; } c; c.f = f;
    unsigned r = (c.u + 0x7fffu + ((c.u >> 16) & 1u)) >> 16;
    return (u16)r;
}
__device__ __forceinline__ unsigned f2bf_fast_u(float f) {
    union { float f; unsigned u; } c; c.f = f;
    return (c.u + 0x8000u) >> 16;
}
__device__ __forceinline__ float wave_sum(float v) {
#pragma unroll
    for (int off = 32; off > 0; off >>= 1) v += __shfl_xor(v, off);
    return v;
}

// ---------------------------------------------------------------------------
// bf16 MFMA GEMM core (R8-FINAL config: 64x64 tile, BK=64, 2-barrier).
// CLOSED after 4 experiments (R3/R4/R7/R9). LDS passed in (R7 lesson);
// bx/by passed for fused-grid remapping. 4 waves each 32x32.
// VTOUT: cols >= 512 written transposed to VT[(col-512)*1024+row], zero-padded.
// ---------------------------------------------------------------------------
template<bool RELU, bool WF32, bool VTOUT>
__device__ __forceinline__ void gemm_core(
    int bx, int by, u16* As, u16* Bs,
    const u16* __restrict__ A0, const u16* __restrict__ A1,
    const u16* __restrict__ A2, int lda0, int lda1, int lda2,
    const u16* __restrict__ W0, const u16* __restrict__ W1,
    const u16* __restrict__ W2, int ldw0, int ldw1, int ldw2,
    int kb1, int kb2,
    const float* __restrict__ bias, float bscale, float cscale,
    float* __restrict__ Cf, u16* __restrict__ Cb, u16* __restrict__ VT,
    int M, int N, int K, int ldc)
{
    const int m0 = by * 64, n0 = bx * 64;
    if (m0 >= M || n0 >= N) return;
    const int t = threadIdx.x, w = t >> 6, l = t & 63;
    const int wm = (w >> 1) * 32, wn = (w & 1) * 32;
    const int li = l & 15, quad = l >> 4;

    f32x4 acc[2][2];
#pragma unroll
    for (int i = 0; i < 2; ++i)
#pragma unroll
        for (int j = 0; j < 2; ++j) acc[i][j] = (f32x4){0.f, 0.f, 0.f, 0.f};

    for (int k0 = 0; k0 < K; k0 += 64) {
        const u16* Ab; const u16* Wb; int ldab, ldwb, ko;
        if (k0 < kb1)      { Ab = A0; ldab = lda0; Wb = W0; ldwb = ldw0; ko = k0; }
        else if (k0 < kb2) { Ab = A1; ldab = lda1; Wb = W1; ldwb = ldw1; ko = k0 - kb1; }
        else               { Ab = A2; ldab = lda2; Wb = W2; ldwb = ldw2; ko = k0 - kb2; }
#pragma unroll
        for (int i = 0; i < 2; ++i) {
            const int rl = w * 16 + i * 8 + (l >> 3);
            const int ck = (l & 7) ^ (rl & 7);
            int ga = m0 + rl; ga = ga < M ? ga : M - 1;
            __builtin_amdgcn_global_load_lds(
                (const __attribute__((address_space(1))) void*)(Ab + (size_t)ga * ldab + ko + ck * 8),
                (__attribute__((address_space(3))) void*)(As + (w * 16 + i * 8) * 64),
                16, 0, 0);
        }
#pragma unroll
        for (int i = 0; i < 2; ++i) {
            const int rl = w * 16 + i * 8 + (l >> 3);
            const int ck = (l & 7) ^ (rl & 7);
            int gb = n0 + rl; gb = gb < N ? gb : N - 1;
            __builtin_amdgcn_global_load_lds(
                (const __attribute__((address_space(1))) void*)(Wb + (size_t)gb * ldwb + ko + ck * 8),
                (__attribute__((address_space(3))) void*)(Bs + (w * 16 + i * 8) * 64),
                16, 0, 0);
        }
        __syncthreads();
#pragma unroll
        for (int ks = 0; ks < 2; ++ks) {
            const int ch = ks * 4 + quad;
            bf16x8 af[2], bfr[2];
#pragma unroll
            for (int mt = 0; mt < 2; ++mt) {
                const int r = wm + mt * 16 + li;
                af[mt] = *(const bf16x8*)(As + r * 64 + ((ch ^ (r & 7)) * 8));
            }
#pragma unroll
            for (int nt = 0; nt < 2; ++nt) {
                const int r = wn + nt * 16 + li;
                bfr[nt] = *(const bf16x8*)(Bs + r * 64 + ((ch ^ (r & 7)) * 8));
            }
#pragma unroll
            for (int mt = 0; mt < 2; ++mt)
#pragma unroll
                for (int nt = 0; nt < 2; ++nt)
                    acc[mt][nt] = __builtin_amdgcn_mfma_f32_16x16x32_bf16(
                        af[mt], bfr[nt], acc[mt][nt], 0, 0, 0);
        }
        __syncthreads();
    }

    float bv[2];
#pragma unroll
    for (int nt = 0; nt < 2; ++nt) bv[nt] = bias[n0 + wn + nt * 16 + li] * bscale;
#pragma unroll
    for (int mt = 0; mt < 2; ++mt) {
        const int row0 = m0 + wm + mt * 16 + quad * 4;
#pragma unroll
        for (int nt = 0; nt < 2; ++nt) {
            const int col = n0 + wn + nt * 16 + li;
            if (VTOUT && col >= 512) {
                ushort4 pk;
                u16 pv[4];
#pragma unroll
                for (int r = 0; r < 4; ++r) {
                    float v = acc[mt][nt][r] * cscale + bv[nt];
                    pv[r] = (row0 + r < M_) ? f2bf(v) : (u16)0;
                }
                pk.x = pv[0]; pk.y = pv[1]; pk.z = pv[2]; pk.w = pv[3];
                *(ushort4*)(VT + (size_t)(col - 512) * 1024 + row0) = pk;
            } else {
#pragma unroll
                for (int r = 0; r < 4; ++r) {
                    const int row = row0 + r;
                    if (row >= M) continue;
                    float v = acc[mt][nt][r] * cscale + bv[nt];
                    if (RELU) v = fmaxf(v, 0.f);
                    Cb[(size_t)row * ldc + col] = f2bf(v);
                    if (WF32) Cf[(size_t)row * ldc + col] = v;
                }
            }
        }
    }
}

template<bool RELU, bool WF32>
__launch_bounds__(256)
__global__ void mgemm(const u16* __restrict__ A0, const u16* __restrict__ A1,
                      const u16* __restrict__ A2, int lda0, int lda1, int lda2,
                      const u16* __restrict__ W0, const u16* __restrict__ W1,
                      const u16* __restrict__ W2, int ldw0, int ldw1, int ldw2,
                      int kb1, int kb2,
                      const float* __restrict__ bias, float bscale, float cscale,
                      float* __restrict__ Cf, u16* __restrict__ Cb,
                      int M, int N, int K, int ldc)
{
    __shared__ u16 As[64 * 64];
    __shared__ u16 Bs[64 * 64];
    gemm_core<RELU, WF32, false>(blockIdx.x, blockIdx.y, As, Bs,
                                 A0, A1, A2, lda0, lda1, lda2,
                                 W0, W1, W2, ldw0, ldw1, ldw2, kb1, kb2,
                                 bias, bscale, cscale, Cf, Cb, nullptr, M, N, K, ldc);
}

// ---------------------------------------------------------------------------
// enc + KV-projection + 3 weight-folds fused in ONE dispatch (single
// kernel-scope LDS). Grid (16,128,2): z=0 enc; z=1: KV + 3 folds.
// ---------------------------------------------------------------------------
__launch_bounds__(256)
__global__ void megagemm(const u16* __restrict__ obs_bf, const u16* __restrict__ w_enc1,
                         const float* __restrict__ enc_b1, u16* __restrict__ hbuf,
                         const u16* __restrict__ wmem_bf, const u16* __restrict__ w_k,
                         const float* __restrict__ bkv, u16* __restrict__ KVbuf,
                         u16* __restrict__ VTb,
                         const u16* __restrict__ w_q, const u16* __restrict__ w_tr1,
                         const u16* __restrict__ w_e2t, const u16* __restrict__ w_wot,
                         u16* __restrict__ w_qe, u16* __restrict__ w_ae,
                         u16* __restrict__ w_co)
{
    __shared__ u16 As[64 * 64];
    __shared__ u16 Bs[64 * 64];
    const int bx = blockIdx.x, by = blockIdx.y;
    if (blockIdx.z == 0) {
        gemm_core<true, false, false>(bx, by, As, Bs,
            obs_bf, obs_bf, obs_bf, 512, 512, 512,
            w_enc1, w_enc1, w_enc1, 512, 512, 512, 512, 512,
            enc_b1, 1.f, 1.f, nullptr, hbuf, nullptr, B_, 512, 512, 512);
    } else {
        if (by < 16) {
            gemm_core<false, false, true>(bx, by, As, Bs,
                wmem_bf, wmem_bf, wmem_bf, 512, 512, 512,
                w_k, w_k, w_k, 512, 512, 512, 512, 512,
                bkv, 1.f, 1.f, nullptr, KVbuf, VTb, 1024, 1024, 512, 1024);
        } else if (by < 24) {
            gemm_core<false, false, false>(bx, by - 16, As, Bs,
                w_q, w_q, w_q, 512, 512, 512,
                w_e2t, w_e2t, w_e2t, 512, 512, 512, 512, 512,
                bkv, 0.f, 1.0f, nullptr, w_qe, nullptr, 512, 512, 512, 512);
        } else if (by < 32) {
            gemm_core<false, false, false>(bx, by - 24, As, Bs,
                w_tr1, w_tr1, w_tr1, 576, 576, 576,
                w_e2t, w_e2t, w_e2t, 512, 512, 512, 512, 512,
                bkv, 0.f, 0.7f, nullptr, w_ae, nullptr, 512, 512, 512, 512);
        } else if (by < 40) {
            gemm_core<false, false, false>(bx, by - 32, As, Bs,
                w_tr1, w_tr1, w_tr1, 576, 576, 576,
                w_wot, w_wot, w_wot, 512, 512, 512, 512, 512,
                bkv, 0.f, 0.3f, nullptr, w_co, nullptr, 512, 512, 512, 512);
        }
    }
}

// ---------------------------------------------------------------------------
// R14: quality head fused (GEMM tile + in-epilogue reduction + sigmoid).
// ---------------------------------------------------------------------------
__launch_bounds__(256)
__global__ void quality_fused(const u16* __restrict__ A,     // nsbf [B_][512]
                              const u16* __restrict__ Wq,    // w_qh [128][512]
                              const float* __restrict__ b1,  // [128]
                              const float* __restrict__ w2,  // [128]
                              const float* __restrict__ b2,  // [1]
                              float* __restrict__ outq)      // [B_]
{
    __shared__ u16 As[64 * 64];
    __shared__ u16 Bs[128 * 64];
    __shared__ float halves[64][2];
    const int m0 = blockIdx.x * 64;
    const int t = threadIdx.x, w = t >> 6, l = t & 63;
    const int wm = (w >> 1) * 32, wn = (w & 1) * 64;
    const int li = l & 15, quad = l >> 4;

    f32x4 acc[2][4];
#pragma unroll
    for (int i = 0; i < 2; ++i)
#pragma unroll
        for (int j = 0; j < 4; ++j) acc[i][j] = (f32x4){0.f, 0.f, 0.f, 0.f};

    for (int k0 = 0; k0 < 512; k0 += 64) {
#pragma unroll
        for (int i = 0; i < 2; ++i) {
            const int rl = w * 16 + i * 8 + (l >> 3);
            const int ck = (l & 7) ^ (rl & 7);
            __builtin_amdgcn_global_load_lds(
                (const __attribute__((address_space(1))) void*)(A + (size_t)(m0 + rl) * 512 + k0 + ck * 8),
                (__attribute__((address_space(3))) void*)(As + (w * 16 + i * 8) * 64),
                16, 0, 0);
        }
#pragma unroll
        for (int i = 0; i < 4; ++i) {
            const int f = i * 256 + t;
            const int rl = f >> 3;                 // 0..127
            const int ck = (f & 7) ^ (rl & 7);
            __builtin_amdgcn_global_load_lds(
                (const __attribute__((address_space(1))) void*)(Wq + (size_t)rl * 512 + k0 + ck * 8),
                (__attribute__((address_space(3))) void*)(Bs + (i * 256 + w * 64) * 8),
                16, 0, 0);
        }
        __syncthreads();
#pragma unroll
        for (int ks = 0; ks < 2; ++ks) {
            const int ch = ks * 4 + quad;
            bf16x8 af[2], bfr[4];
#pragma unroll
            for (int mt = 0; mt < 2; ++mt) {
                const int r = wm + mt * 16 + li;
                af[mt] = *(const bf16x8*)(As + r * 64 + ((ch ^ (r & 7)) * 8));
            }
#pragma unroll
            for (int nt = 0; nt < 4; ++nt) {
                const int r = wn + nt * 16 + li;
                bfr[nt] = *(const bf16x8*)(Bs + r * 64 + ((ch ^ (r & 7)) * 8));
            }
#pragma unroll
            for (int mt = 0; mt < 2; ++mt)
#pragma unroll
                for (int nt = 0; nt < 4; ++nt)
                    acc[mt][nt] = __builtin_amdgcn_mfma_f32_16x16x32_bf16(
                        af[mt], bfr[nt], acc[mt][nt], 0, 0, 0);
        }
        __syncthreads();
    }

    float part[2][4];
#pragma unroll
    for (int mt = 0; mt < 2; ++mt)
#pragma unroll
        for (int r = 0; r < 4; ++r) part[mt][r] = 0.f;
#pragma unroll
    for (int nt = 0; nt < 4; ++nt) {
        const int col = wn + nt * 16 + li;
        const float wv = w2[col];
        const float bb = b1[col];
#pragma unroll
        for (int mt = 0; mt < 2; ++mt)
#pragma unroll
            for (int r = 0; r < 4; ++r)
                part[mt][r] += fmaxf(acc[mt][nt][r] + bb, 0.f) * wv;
    }
#pragma unroll
    for (int off = 1; off < 16; off <<= 1)
#pragma unroll
        for (int mt = 0; mt < 2; ++mt)
#pragma unroll
            for (int r = 0; r < 4; ++r)
                part[mt][r] += __shfl_xor(part[mt][r], off);
    if (li == 0) {
#pragma unroll
        for (int mt = 0; mt < 2; ++mt)
#pragma unroll
            for (int r = 0; r < 4; ++r)
                halves[wm + mt * 16 + quad * 4 + r][w & 1] = part[mt][r];
    }
    __syncthreads();
    if (t < 64) {
        const float s = halves[t][0] + halves[t][1] + b2[0];
        outq[m0 + t] = 1.0f / (1.0f + expf(-s));
    }
}

// ---------------------------------------------------------------------------
// Fused flash attention. R15: 128 keys per iteration as TWO 64-key
// sub-chunks -> barriers halve 16->8. R14 counters: occupancy doubled (33%)
// but dur flat at 43us -> per-chunk vmcnt(0)+barrier drain dominates (~6.4k
// cyc/chunk vs ~1.5k issue). Sub-chunks share one barrier: P is PER-WAVE,
// so sub1's P overwrite after sub0's PV needs only intra-wave lgkm ordering
// (no barrier). All 64-key sub-buffer layouts/swizzles byte-identical to
// the proven pattern. LDS 48->80KB: residency unchanged (512-thr blocks cap
// at 2/CU; grid 512 = 2/CU exactly). Mask moves to ic==7&&sub==1.
// R13 8-wave structure, R11 Q-prologue, R10 setprio all unchanged.
// ---------------------------------------------------------------------------
__launch_bounds__(512, 2)
__global__ void attn_kernel(const u16* __restrict__ hn, const u16* __restrict__ w_qe,
                            const float* __restrict__ bqe,
                            const u16* __restrict__ KV,
                            const u16* __restrict__ VT, u16* __restrict__ ctx)
{
    __shared__ u16 Ks[2][2][64 * 64];
    __shared__ u16 Vs[2][2][64 * 64];
    __shared__ u16 P[128 * 64];
    const int t = threadIdx.x, w = t >> 6, l = t & 63;
    const int h = blockIdx.y;
    const int q0b = blockIdx.x * 128;
    u16* Pw = P + w * 1024;
    const int li = l & 15, quad = l >> 4;

    // stage a 128-key chunk as two 64-key sub-buffers (proven 64x64 pattern).
    auto stage = [&](int kc, int buf) {
#pragma unroll
        for (int sub = 0; sub < 2; ++sub) {
            const int r = t >> 3;
            const int ck = (t & 7) ^ (r & 7);
            __builtin_amdgcn_global_load_lds(
                (const __attribute__((address_space(1))) void*)(KV + (size_t)(kc + sub * 64 + r) * 1024 + h * 64 + ck * 8),
                (__attribute__((address_space(3))) void*)(&Ks[buf][sub][t * 8]),
                16, 0, 0);
            __builtin_amdgcn_global_load_lds(
                (const __attribute__((address_space(1))) void*)(VT + (size_t)(h * 64 + r) * 1024 + kc + sub * 64 + ck * 8),
                (__attribute__((address_space(3))) void*)(&Vs[buf][sub][t * 8]),
                16, 0, 0);
        }
    };

    // ---- Q-projection prologue (R11/R13-proven)
    {
        u16* Ksf = &Ks[0][0][0];          // 128x64 A-tile (16KB, spans Ks[0][0..1])
        u16* Bsf = &Vs[0][0][0];          // 64x64 B-tile
        f32x4 qacc[4];
#pragma unroll
        for (int nt = 0; nt < 4; ++nt) qacc[nt] = (f32x4){0.f, 0.f, 0.f, 0.f};

        for (int k0 = 0; k0 < 512; k0 += 64) {
#pragma unroll
            for (int i = 0; i < 2; ++i) {
                const int f = i * 512 + t;
                const int rl = f >> 3;
                const int ck = (f & 7) ^ (rl & 7);
                __builtin_amdgcn_global_load_lds(
                    (const __attribute__((address_space(1))) void*)(hn + (size_t)(q0b + rl) * 512 + k0 + ck * 8),
                    (__attribute__((address_space(3))) void*)(Ksf + f * 8),
                    16, 0, 0);
            }
            {
                const int rl = t >> 3;
                const int ck = (t & 7) ^ (rl & 7);
                __builtin_amdgcn_global_load_lds(
                    (const __attribute__((address_space(1))) void*)(w_qe + (size_t)(h * 64 + rl) * 512 + k0 + ck * 8),
                    (__attribute__((address_space(3))) void*)(Bsf + t * 8),
                    16, 0, 0);
            }
            __syncthreads();
            __builtin_amdgcn_s_setprio(1);
#pragma unroll
            for (int ks = 0; ks < 2; ++ks) {
                const int ch = ks * 4 + quad;
                const int r = w * 16 + li;
                const bf16x8 af = *(const bf16x8*)(Ksf + r * 64 + ((ch ^ (r & 7)) * 8));
                bf16x8 bfr[4];
#pragma unroll
                for (int nt = 0; nt < 4; ++nt) {
                    const int rb = nt * 16 + li;
                    bfr[nt] = *(const bf16x8*)(Bsf + rb * 64 + ((ch ^ (rb & 7)) * 8));
                }
#pragma unroll
                for (int nt = 0; nt < 4; ++nt)
                    qacc[nt] = __builtin_amdgcn_mfma_f32_16x16x32_bf16(
                        af, bfr[nt], qacc[nt], 0, 0, 0);
            }
            __builtin_amdgcn_s_setprio(0);
            __syncthreads();
        }

        stage(0, 0);

#pragma unroll
        for (int nt = 0; nt < 4; ++nt) {
            const int col = nt * 16 + li;
            const float bv = bqe[h * 64 + col];
#pragma unroll
            for (int r = 0; r < 4; ++r) {
                const int row = w * 16 + quad * 4 + r;
                P[row * 64 + (((2 * nt + (li >> 3)) ^ (row & 7)) * 8) + (li & 7)] =
                    f2bf(qacc[nt][r] + bv);
            }
        }
    }

    bf16x8 aq[2];
#pragma unroll
    for (int ks = 0; ks < 2; ++ks) {
        const int row = w * 16 + li;
        aq[ks] = *(const bf16x8*)(P + row * 64 + (((ks * 4 + quad) ^ (li & 7)) * 8));
    }

    bf16x8 ones;
#pragma unroll
    for (int i = 0; i < 8; ++i) ones[i] = (short)0x3F80;

    f32x4 oacc[4];
    f32x4 lacc = (f32x4){0.f, 0.f, 0.f, 0.f};
#pragma unroll
    for (int nt = 0; nt < 4; ++nt) oacc[nt] = (f32x4){0.f, 0.f, 0.f, 0.f};

    for (int ic = 0; ic < 8; ++ic) {
        const int kc = ic * 128;
        __syncthreads();          // chunk-ic staging drained; aq/P reads done
        if (ic < 7) stage(kc + 128, (ic + 1) & 1);
#pragma unroll
        for (int sub = 0; sub < 2; ++sub) {
            const u16* ksb = &Ks[ic & 1][sub][0];
            const u16* vsb = &Vs[ic & 1][sub][0];

            f32x4 s[4];
#pragma unroll
            for (int kmt = 0; kmt < 4; ++kmt) s[kmt] = (f32x4){0.f, 0.f, 0.f, 0.f};
            __builtin_amdgcn_s_setprio(1);
#pragma unroll
            for (int ks = 0; ks < 2; ++ks) {
                const int ch = ks * 4 + quad;
                bf16x8 bk[4];
#pragma unroll
                for (int kmt = 0; kmt < 4; ++kmt) {
                    const int key = kmt * 16 + li;
                    bk[kmt] = *(const bf16x8*)(ksb + key * 64 + ((ch ^ (key & 7)) * 8));
                }
#pragma unroll
                for (int kmt = 0; kmt < 4; ++kmt)
                    s[kmt] = __builtin_amdgcn_mfma_f32_16x16x32_bf16(
                        bk[kmt], aq[ks], s[kmt], 0, 0, 0);
            }
            __builtin_amdgcn_s_setprio(0);
            if (ic == 7 && sub == 1) {    // keys 960..1023: mask >= M_
#pragma unroll
                for (int kmt = 2; kmt < 4; ++kmt)
#pragma unroll
                    for (int r = 0; r < 4; ++r) {
                        const int key_local = kmt * 16 + quad * 4 + r;
                        if (960 + key_local >= M_) s[kmt][r] = -3.0e38f;
                    }
            }
#pragma unroll
            for (int kmt = 0; kmt < 4; ++kmt) {
                const unsigned b0 = f2bf_fast_u(exp2f(s[kmt][0]));
                const unsigned b1 = f2bf_fast_u(exp2f(s[kmt][1]));
                const unsigned b2w = f2bf_fast_u(exp2f(s[kmt][2]));
                const unsigned b3 = f2bf_fast_u(exp2f(s[kmt][3]));
                const int chunk = (2 * kmt + (quad >> 1)) ^ (li & 7);
                const int off = li * 64 + chunk * 8 + (quad & 1) * 4;
                *(uint2*)(Pw + off) = make_uint2(b0 | (b1 << 16), b2w | (b3 << 16));
            }
            __builtin_amdgcn_s_setprio(1);
#pragma unroll
            for (int ks = 0; ks < 2; ++ks) {
                const int ch = ks * 4 + quad;
                const bf16x8 ap = *(const bf16x8*)(Pw + li * 64 + ((ch ^ (li & 7)) * 8));
                lacc = __builtin_amdgcn_mfma_f32_16x16x32_bf16(ap, ones, lacc, 0, 0, 0);
#pragma unroll
                for (int nt = 0; nt < 4; ++nt) {
                    const int dh = nt * 16 + li;
                    const bf16x8 bvv = *(const bf16x8*)(vsb + dh * 64 + ((ch ^ (dh & 7)) * 8));
                    oacc[nt] = __builtin_amdgcn_mfma_f32_16x16x32_bf16(
                        ap, bvv, oacc[nt], 0, 0, 0);
                }
            }
            __builtin_amdgcn_s_setprio(0);
        }
    }

#pragma unroll
    for (int r = 0; r < 4; ++r) {
        const int row = q0b + w * 16 + quad * 4 + r;
        const float inv = 1.0f / lacc[r];
#pragma unroll
        for (int nt = 0; nt < 4; ++nt)
            ctx[(size_t)row * 512 + h * 64 + nt * 16 + li] = f2bf(oacc[nt][r] * inv);
    }
}

__launch_bounds__(256)
__global__ void ln_bf(u16* __restrict__ X, const float* __restrict__ g,
                      const float* __restrict__ be, int rows)
{
    const int row = blockIdx.x * 4 + (threadIdx.x >> 6);
    const int lane = threadIdx.x & 63;
    if (row >= rows) return;
    u16* p = X + (size_t)row * 512 + lane * 8;
    uint4 d = *(const uint4*)p;
    const unsigned dd[4] = {d.x, d.y, d.z, d.w};
    float v[8];
#pragma unroll
    for (int i = 0; i < 4; ++i) {
        v[2 * i]     = bf2f((u16)(dd[i] & 0xffffu));
        v[2 * i + 1] = bf2f((u16)(dd[i] >> 16));
    }
    float s = 0.f;
#pragma unroll
    for (int i = 0; i < 8; ++i) s += v[i];
    s = wave_sum(s);
    const float mu = s * (1.0f / 512.0f);
    float vs = 0.f;
#pragma unroll
    for (int i = 0; i < 8; ++i) { v[i] -= mu; vs += v[i] * v[i]; }
    vs = wave_sum(vs);
    const float r = rsqrtf(vs * (1.0f / 512.0f) + 1e-5f);
    const float* gp = g + lane * 8;
    const float* bp = be + lane * 8;
    unsigned o[4];
#pragma unroll
    for (int i = 0; i < 4; ++i) {
        const u16 lo = f2bf(v[2 * i] * r * gp[2 * i] + bp[2 * i]);
        const u16 hi = f2bf(v[2 * i + 1] * r * gp[2 * i + 1] + bp[2 * i + 1]);
        o[i] = (unsigned)lo | ((unsigned)hi << 16);
    }
    *(uint4*)p = make_uint4(o[0], o[1], o[2], o[3]);
}

// one-dispatch prep: weight converts (0-6), transposes (7-8), activation
// converts (9-11), bias folds (12-13)  (R6-exact)
__launch_bounds__(256)
__global__ void prep_all(const float* enc_w1, const float* wk_f, const float* wv_f,
                         const float* tr_w2, const float* q_w1, const float* wq,
                         const float* tr_w1, const float* enc_w2, const float* wo,
                         const float* obs, const float* wmem, const float* ego,
                         const float* bk, const float* bvv, const float* bq,
                         const float* enc_b2, const float* trb1, const float* bo,
                         u16* w_enc1, u16* w_k, u16* w_v, u16* w_tr2, u16* w_qh,
                         u16* w_q, u16* w_tr1, u16* w_e2t, u16* w_wot,
                         u16* obs_bf, u16* wmem_bf, u16* ego64,
                         float* bkv, float* bqe, float* btr)
{
    __shared__ float tl[64][65];
    const int seg = blockIdx.y;
    const int t = threadIdx.x;
    const int bx = blockIdx.x;

    if (seg <= 5) {
        const float* s; u16* d; int n; float sc = 1.0f;
        switch (seg) {
            case 0: s = enc_w1; d = w_enc1; n = 262144; break;
            case 1: s = wk_f;   d = w_k;    n = 262144; break;
            case 2: s = wv_f;   d = w_v;    n = 262144; break;
            case 3: s = tr_w2;  d = w_tr2;  n = 262144; break;
            case 4: s = q_w1;   d = w_qh;   n = 65536;  break;
            default: s = wq;    d = w_q;    n = 262144; sc = 0.125f * LOG2E; break;
        }
        const int i0 = (bx * 256 + t) * 4;
        if (i0 + 3 < n) {
            const float4 v = *(const float4*)(s + i0);
            ushort4 o;
            o.x = f2bf(v.x * sc); o.y = f2bf(v.y * sc);
            o.z = f2bf(v.z * sc); o.w = f2bf(v.w * sc);
            *(ushort4*)(d + i0) = o;
        }
    } else if (seg == 6) {
#pragma unroll
        for (int k = 0; k < 4; ++k) {
            const int i = (bx * 256 + t) * 4 + k;
            if (i < 294912) {
                const int r = i / 576, c = i - r * 576;
                w_tr1[i] = (c < 528) ? f2bf(tr_w1[r * 528 + c]) : (u16)0;
            }
        }
    } else if (seg <= 8) {
        if (bx >= 64) return;
        const float* S = (seg == 7) ? enc_w2 : wo;
        u16* D = (seg == 7) ? w_e2t : w_wot;
        const int r0 = (bx >> 3) * 64, c0 = (bx & 7) * 64;
#pragma unroll
        for (int i = 0; i < 16; ++i) {
            const int idx = t + i * 256;
            tl[idx >> 6][idx & 63] = S[(size_t)(r0 + (idx >> 6)) * 512 + c0 + (idx & 63)];
        }
        __syncthreads();
#pragma unroll
        for (int i = 0; i < 16; ++i) {
            const int idx = t + i * 256;
            const int c = idx >> 6, r = idx & 63;
            D[(size_t)(c0 + c) * 512 + r0 + r] = f2bf(tl[r][c]);
        }
    } else if (seg == 9) {
        const int nth = gridDim.x * 256;
        for (int i = bx * 256 + t; i < B_ * 512 / 4; i += nth) {
            const float4 v = ((const float4*)obs)[i];
            ushort4 o;
            o.x = f2bf(v.x); o.y = f2bf(v.y); o.z = f2bf(v.z); o.w = f2bf(v.w);
            ((ushort4*)obs_bf)[i] = o;
        }
    } else if (seg == 10) {
        const int nth = gridDim.x * 256;
        for (int i = bx * 256 + t; i < M_ * 512 / 4; i += nth) {
            const float4 v = ((const float4*)wmem)[i];
            ushort4 o;
            o.x = f2bf(v.x); o.y = f2bf(v.y); o.z = f2bf(v.z); o.w = f2bf(v.w);
            ((ushort4*)wmem_bf)[i] = o;
        }
    } else if (seg == 11) {
        const int nth = gridDim.x * 256;
        for (int i = bx * 256 + t; i < B_ * 64; i += nth) {
            const int b = i >> 6, j = i & 63;
            ego64[(size_t)b * 64 + j] = (j < 16) ? f2bf(ego[b * 16 + j]) : (u16)0;
        }
        const int tid = bx * 256 + t;
        if (tid < 1024) bkv[tid] = (tid < 512) ? bk[tid] : bvv[tid - 512];
    } else {
        if (bx >= 128) return;
        const int i = bx * 4 + (t >> 6);
        const int lane = t & 63;
        float s = 0.f;
        if (seg == 12) {
            const float* wr = wq + (size_t)i * 512 + lane * 8;
#pragma unroll
            for (int j = 0; j < 8; ++j) s += wr[j] * enc_b2[lane * 8 + j];
            s = wave_sum(s);
            if (lane == 0) bqe[i] = 0.125f * LOG2E * (bq[i] + s);
        } else {
            const float* wr = tr_w1 + (size_t)i * 528 + lane * 8;
#pragma unroll
            for (int j = 0; j < 8; ++j)
                s += wr[j] * (0.7f * enc_b2[lane * 8 + j] + 0.3f * bo[lane * 8 + j]);
            s = wave_sum(s);
            if (lane == 0) btr[i] = trb1[i] + s;
        }
    }
}

__global__ void compact_kernel(const float* __restrict__ q,
                               int* __restrict__ list, int* __restrict__ cnt)
{
    __shared__ int wtot[16];
    __shared__ int sbase;
    const int t = threadIdx.x, w = t >> 6, lane = t & 63;
    if (t == 0) sbase = 0;
    __syncthreads();
    for (int c = 0; c < B_; c += 1024) {
        const int idx = c + t;
        const bool pred = (q[idx] > 0.7f);
        const unsigned long long bal = __ballot(pred);
        const int prefix = __popcll(bal & ((1ull << lane) - 1ull));
        if (lane == 0) wtot[w] = __popcll(bal);
        __syncthreads();
        int woff = 0;
        for (int i = 0; i < w; ++i) woff += wtot[i];
        if (pred) list[sbase + woff + prefix] = idx;
        __syncthreads();
        if (t == 0) {
            int tot = 0;
            for (int i = 0; i < 16; ++i) tot += wtot[i];
            sbase += tot;
        }
        __syncthreads();
    }
    if (t == 0) *cnt = sbase;
}

__global__ void update_memory_kernel(const float* __restrict__ mem,
                                     const float* __restrict__ ns,
                                     const int* __restrict__ upd,
                                     const int* __restrict__ list,
                                     const int* __restrict__ cnt,
                                     float* __restrict__ outmem)
{
    const int m = blockIdx.x;
    const int t = threadIdx.x;
    const int c4 = t * 4;
    float4 r = *(const float4*)(mem + (size_t)m * D_ + c4);
    const int n = *cnt;
    for (int i = 0; i < n; ++i) {
        const int b = list[i];
        if (upd[b] == m) {
            const float4 s = *(const float4*)(ns + (size_t)b * D_ + c4);
            r.x = 0.9f * r.x + 0.1f * s.x;
            r.y = 0.9f * r.y + 0.1f * s.y;
            r.z = 0.9f * r.z + 0.1f * s.z;
            r.w = 0.9f * r.w + 0.1f * s.w;
        }
    }
    *(float4*)(outmem + (size_t)m * D_ + c4) = r;
}

extern "C" void kernel_launch(void* const* d_in, const int* in_sizes, int n_in,
                              void* d_out, int out_size, void* d_ws, size_t ws_size,
                              hipStream_t stream)
{
    const float* obs    = (const float*)d_in[0];
    const float* ego    = (const float*)d_in[1];
    const float* wmem   = (const float*)d_in[2];
    const float* enc_w1 = (const float*)d_in[3];
    const float* enc_b1 = (const float*)d_in[4];
    const float* enc_g  = (const float*)d_in[5];
    const float* enc_be = (const float*)d_in[6];
    const float* enc_w2 = (const float*)d_in[7];
    const float* enc_b2 = (const float*)d_in[8];
    const float* wq = (const float*)d_in[9];
    const float* bq = (const float*)d_in[10];
    const float* wk_f = (const float*)d_in[11];
    const float* bk = (const float*)d_in[12];
    const float* wv_f = (const float*)d_in[13];
    const float* bvv = (const float*)d_in[14];
    const float* wo = (const float*)d_in[15];
    const float* bo = (const float*)d_in[16];
    const float* tr_w1 = (const float*)d_in[17];
    const float* tr_b1 = (const float*)d_in[18];
    const float* tr_g  = (const float*)d_in[19];
    const float* tr_be = (const float*)d_in[20];
    const float* tr_w2 = (const float*)d_in[21];
    const float* tr_b2 = (const float*)d_in[22];
    const float* q_w1 = (const float*)d_in[23];
    const float* q_b1 = (const float*)d_in[24];
    const float* q_w2 = (const float*)d_in[25];
    const float* q_b2 = (const float*)d_in[26];
    const int*   upd  = (const int*)d_in[27];

    float* out_ns  = (float*)d_out;
    float* out_q   = out_ns + (size_t)B_ * D_;
    float* out_mem = out_q + B_;

    u16* ws = (u16*)d_ws;
    size_t o = 0;
    u16* obs_bf  = ws + o; o += (size_t)B_ * 512;
    u16* wmem_bf = ws + o; o += (size_t)M_ * 512;
    u16* w_enc1  = ws + o; o += 262144;
    u16* w_k     = ws + o; o += 262144;   // contiguous with w_v -> fused KV weight
    u16* w_v     = ws + o; o += 262144;
    u16* w_tr2   = ws + o; o += 262144;
    u16* w_qh    = ws + o; o += 65536;
    u16* w_q     = ws + o; o += 262144;
    u16* w_tr1   = ws + o; o += (size_t)512 * 576;
    u16* w_e2t   = ws + o; o += 262144;
    u16* w_wot   = ws + o; o += 262144;
    u16* w_qe    = ws + o; o += 262144;
    u16* w_ae    = ws + o; o += 262144;
    u16* w_co    = ws + o; o += 262144;
    u16* hbuf    = ws + o; o += (size_t)B_ * 512;
    u16* qbuf    = ws + o; o += (size_t)B_ * 512;   // unused since R11 (layout stability)
    u16* KVbuf   = ws + o; o += (size_t)1024 * 1024;
    u16* VTb     = ws + o; o += (size_t)512 * 1024;
    u16* ctx     = ws + o; o += (size_t)B_ * 512;
    u16* h2b     = ws + o; o += (size_t)B_ * 512;
    u16* nsbf    = ws + o; o += (size_t)B_ * 512;
    u16* qhb     = ws + o; o += (size_t)B_ * 128;   // unused since R14
    u16* ego64   = ws + o; o += (size_t)B_ * 64;
    float* bkv   = (float*)(ws + o); o += 2048;
    float* bqe   = (float*)(ws + o); o += 1024;
    float* btr   = (float*)(ws + o); o += 1024;
    int* list    = (int*)(ws + o);
    int* cnt     = list + B_;
    (void)qbuf; (void)qhb;

    const dim3 blk(256);

    prep_all<<<dim3(576, 14), blk, 0, stream>>>(
        enc_w1, wk_f, wv_f, tr_w2, q_w1, wq, tr_w1, enc_w2, wo,
        obs, wmem, ego, bk, bvv, bq, enc_b2, tr_b1, bo,
        w_enc1, w_k, w_v, w_tr2, w_qh, w_q, w_tr1, w_e2t, w_wot,
        obs_bf, wmem_bf, ego64, bkv, bqe, btr);

    megagemm<<<dim3(16, 128, 2), blk, 0, stream>>>(
        obs_bf, w_enc1, enc_b1, hbuf, wmem_bf, w_k, bkv, KVbuf, VTb,
        w_q, w_tr1, w_e2t, w_wot, w_qe, w_ae, w_co);

    ln_bf<<<dim3(2048), blk, 0, stream>>>(hbuf, enc_g, enc_be, B_);

    attn_kernel<<<dim3(64, 8), dim3(512), 0, stream>>>(hbuf, w_qe, bqe, KVbuf, VTb, ctx);

    mgemm<true, false><<<dim3(8, 128), blk, 0, stream>>>(
        hbuf, ctx, ego64, 512, 512, 64, w_ae, w_co, w_tr1 + 512, 512, 512, 576,
        512, 1024, btr, 1.f, 1.f, nullptr, h2b, B_, 512, 1088, 512);
    ln_bf<<<dim3(2048), blk, 0, stream>>>(h2b, tr_g, tr_be, B_);

    mgemm<false, true><<<dim3(8, 128), blk, 0, stream>>>(
        h2b, h2b, h2b, 512, 512, 512, w_tr2, w_tr2, w_tr2, 512, 512, 512,
        512, 512, tr_b2, 1.f, 1.f, out_ns, nsbf, B_, 512, 512, 512);

    quality_fused<<<dim3(128), blk, 0, stream>>>(nsbf, w_qh, q_b1, q_w2, q_b2, out_q);

    compact_kernel<<<dim3(1), dim3(1024), 0, stream>>>(out_q, list, cnt);
    update_memory_kernel<<<dim3(M_), dim3(128), 0, stream>>>(
        wmem, out_ns, upd, list, cnt, out_mem);
}